// Round 1
// baseline (2652.707 us; speedup 1.0000x reference)
//
#include <hip/hip_runtime.h>
#include <hip/hip_bf16.h>

typedef unsigned short u16;
typedef unsigned int   u32;

#define B_SZ  2
#define L_SEQ 1024
#define D_EMB 768
#define KF    16

// ---- helpers ----
__device__ __forceinline__ u16 f2bf(float f) {
    u32 u = __float_as_uint(f);
    u32 r = (u + 0x7FFFu + ((u >> 16) & 1u)) >> 16;   // RNE
    return (u16)r;
}
__device__ __forceinline__ float bf2f(u16 v) {
    return __uint_as_float(((u32)v) << 16);
}

// =====================================================================
// Stage 1: causal conv.  U_plus[b,t,k,d] = sum_{s=0..t} phi[s,k] x[b,t-s,d]
//          U_minus same with (-1)^s phi[s,k].
// Block: 64 t x 64 d tile for one (b,k). 256 threads: tg=t-row(64), dg=4 d-groups of 16.
// =====================================================================
__global__ __launch_bounds__(256) void stu_conv(const float* __restrict__ x,
                                                const float* __restrict__ phi,
                                                u16* __restrict__ Up,
                                                u16* __restrict__ Um) {
    __shared__ __align__(16) float xs[64][68];
    __shared__ float php[128];
    __shared__ float phm[128];

    const int t0 = blockIdx.x << 6;
    const int b  = blockIdx.y >> 4;
    const int k  = blockIdx.y & 15;
    const int d0 = blockIdx.z << 6;
    const int tid = threadIdx.x;
    const int tg = tid >> 2;          // 0..63 : t row within tile
    const int dg = (tid & 3) << 4;    // 0,16,32,48 : d sub-block

    float accp[16], accm[16];
#pragma unroll
    for (int i = 0; i < 16; ++i) { accp[i] = 0.f; accm[i] = 0.f; }

    const float* xb = x + (size_t)b * L_SEQ * D_EMB + d0;

    for (int r0 = 0; r0 <= t0; r0 += 64) {
        __syncthreads();
        // stage x[b, r0..r0+63, d0..d0+63]
#pragma unroll
        for (int j = 0; j < 4; ++j) {
            int c   = tid + (j << 8);          // 0..1023
            int row = c >> 4;
            int col = (c & 15) << 2;
            *(float4*)&xs[row][col] =
                *(const float4*)&xb[(size_t)(r0 + row) * D_EMB + col];
        }
        // stage phi window: j in [0,128), s = t0-r0-63+j
        if (tid < 128) {
            int s = t0 - r0 - 63 + tid;
            float v = (s >= 0 && s < L_SEQ) ? phi[s * KF + k] : 0.f;
            php[tid] = v;
            phm[tid] = (s & 1) ? -v : v;
        }
        __syncthreads();

#pragma unroll 4
        for (int rr = 0; rr < 64; ++rr) {
            const int j = 63 + tg - rr;        // phi index: s = t - r
            const float p = php[j];
            const float m = phm[j];
#pragma unroll
            for (int q = 0; q < 4; ++q) {
                const float4 xv = *(const float4*)&xs[rr][dg + (q << 2)];
                accp[q*4+0] += p * xv.x; accp[q*4+1] += p * xv.y;
                accp[q*4+2] += p * xv.z; accp[q*4+3] += p * xv.w;
                accm[q*4+0] += m * xv.x; accm[q*4+1] += m * xv.y;
                accm[q*4+2] += m * xv.z; accm[q*4+3] += m * xv.w;
            }
        }
    }

    // store bf16 U tiles: U[((b*L+t)*K + k)*D + d]
    const int t = t0 + tg;
    size_t base = (((size_t)(b * L_SEQ + t)) * KF + k) * D_EMB + d0 + dg;
    u16 bp[16], bm[16];
#pragma unroll
    for (int i = 0; i < 16; ++i) { bp[i] = f2bf(accp[i]); bm[i] = f2bf(accm[i]); }
    *(uint4*)&Up[base]     = *(uint4*)&bp[0];
    *(uint4*)&Up[base + 8] = *(uint4*)&bp[8];
    *(uint4*)&Um[base]     = *(uint4*)&bm[0];
    *(uint4*)&Um[base + 8] = *(uint4*)&bm[8];
}

// =====================================================================
// Stage 2: out[m,o] += sum_{k,i} Up[m,k,i] Mp[k,o,i] + Um[m,k,i] Mm[k,o,i]
// m = b*L+l (2048 rows). C-tile 128m x 64o, contraction over kz half (8 k's).
// 256 threads: each 8m x 4o. A staged transposed [ii][m], B staged [ii][o].
// =====================================================================
__global__ __launch_bounds__(256) void stu_spectral(const u16* __restrict__ Up,
                                                    const u16* __restrict__ Um,
                                                    const float* __restrict__ Mp,
                                                    const float* __restrict__ Mm,
                                                    float* __restrict__ out) {
    __shared__ __align__(16) float Asp[32][132];
    __shared__ __align__(16) float Asm_[32][132];
    __shared__ __align__(16) float Bsp[32][68];
    __shared__ __align__(16) float Bsm[32][68];

    const int m0 = blockIdx.x << 7;      // 128 rows
    const int o0 = blockIdx.y << 6;      // 64 cols
    const int kz = blockIdx.z;           // 0..1
    const int tid = threadIdx.x;
    const int tm = (tid >> 4) << 3;      // 0..120 (8 rows per thread)
    const int to = (tid & 15) << 2;      // 0..60  (4 cols per thread)

    const int arow = tid >> 1;           // 0..127
    const int aih  = (tid & 1) << 4;     // 0 or 16

    float acc[32];
#pragma unroll
    for (int i = 0; i < 32; ++i) acc[i] = 0.f;

    for (int k = kz * 8; k < kz * 8 + 8; ++k) {
        for (int ic = 0; ic < D_EMB; ic += 32) {
            __syncthreads();
            // ---- stage A (bf16 -> f32, transposed) ----
            {
                size_t ga = ((size_t)(m0 + arow) * KF + k) * D_EMB + ic + aih;
                uint4 rp0 = *(const uint4*)&Up[ga];
                uint4 rp1 = *(const uint4*)&Up[ga + 8];
                uint4 rm0 = *(const uint4*)&Um[ga];
                uint4 rm1 = *(const uint4*)&Um[ga + 8];
                u16 av[16], bv[16];
                *(uint4*)&av[0] = rp0; *(uint4*)&av[8] = rp1;
                *(uint4*)&bv[0] = rm0; *(uint4*)&bv[8] = rm1;
#pragma unroll
                for (int j = 0; j < 16; ++j) {
                    Asp [aih + j][arow] = bf2f(av[j]);
                    Asm_[aih + j][arow] = bf2f(bv[j]);
                }
            }
            // ---- stage B (f32, transposed to [ii][o]) ----
#pragma unroll
            for (int j = 0; j < 2; ++j) {
                int c  = tid + (j << 8);     // 0..511
                int ro = c >> 3;             // 0..63
                int ci = (c & 7) << 2;       // 0..28
                size_t gb = ((size_t)k * D_EMB + o0 + ro) * D_EMB + ic + ci;
                const float4 vp = *(const float4*)&Mp[gb];
                const float4 vm = *(const float4*)&Mm[gb];
                Bsp[ci+0][ro] = vp.x; Bsp[ci+1][ro] = vp.y;
                Bsp[ci+2][ro] = vp.z; Bsp[ci+3][ro] = vp.w;
                Bsm[ci+0][ro] = vm.x; Bsm[ci+1][ro] = vm.y;
                Bsm[ci+2][ro] = vm.z; Bsm[ci+3][ro] = vm.w;
            }
            __syncthreads();

#pragma unroll 8
            for (int ii = 0; ii < 32; ++ii) {
                const float4 bp  = *(const float4*)&Bsp[ii][to];
                const float4 bm  = *(const float4*)&Bsm[ii][to];
                const float4 ap0 = *(const float4*)&Asp[ii][tm];
                const float4 ap1 = *(const float4*)&Asp[ii][tm + 4];
                const float4 am0 = *(const float4*)&Asm_[ii][tm];
                const float4 am1 = *(const float4*)&Asm_[ii][tm + 4];
                const float apv[8] = {ap0.x,ap0.y,ap0.z,ap0.w, ap1.x,ap1.y,ap1.z,ap1.w};
                const float amv[8] = {am0.x,am0.y,am0.z,am0.w, am1.x,am1.y,am1.z,am1.w};
                const float bpv[4] = {bp.x,bp.y,bp.z,bp.w};
                const float bmv[4] = {bm.x,bm.y,bm.z,bm.w};
#pragma unroll
                for (int q = 0; q < 8; ++q)
#pragma unroll
                    for (int j = 0; j < 4; ++j)
                        acc[q*4+j] += apv[q]*bpv[j] + amv[q]*bmv[j];
            }
        }
    }

    // accumulate partials (two kz blocks per C-tile)
#pragma unroll
    for (int q = 0; q < 8; ++q) {
        size_t ob = (size_t)(m0 + tm + q) * D_EMB + o0 + to;
#pragma unroll
        for (int j = 0; j < 4; ++j)
            atomicAdd(&out[ob + j], acc[q*4+j]);
    }
}

extern "C" void kernel_launch(void* const* d_in, const int* in_sizes, int n_in,
                              void* d_out, int out_size, void* d_ws, size_t ws_size,
                              hipStream_t stream) {
    const float* x   = (const float*)d_in[0];
    const float* phi = (const float*)d_in[1];
    const float* Mp  = (const float*)d_in[2];
    const float* Mm  = (const float*)d_in[3];
    float* out = (float*)d_out;

    const size_t S = (size_t)B_SZ * L_SEQ * KF * D_EMB;  // 25,165,824 elems
    u16* Up = (u16*)d_ws;
    u16* Um = Up + S;                                    // total 96 MB of ws

    hipMemsetAsync(d_out, 0, (size_t)out_size * sizeof(float), stream);

    dim3 g1(L_SEQ / 64, B_SZ * KF, D_EMB / 64);          // 16 x 32 x 12
    stu_conv<<<g1, dim3(256), 0, stream>>>(x, phi, Up, Um);

    dim3 g2((B_SZ * L_SEQ) / 128, D_EMB / 64, 2);        // 16 x 12 x 2
    stu_spectral<<<g2, dim3(256), 0, stream>>>(Up, Um, Mp, Mm, out);
}

// Round 3
// 1117.591 us; speedup vs baseline: 2.3736x; 2.3736x over previous
//
#include <hip/hip_runtime.h>
#include <hip/hip_fp16.h>

typedef unsigned short u16;
typedef unsigned int   u32;
typedef _Float16 f16;
typedef __attribute__((ext_vector_type(8))) f16 f16x8;
typedef __attribute__((ext_vector_type(2))) __fp16 fp16x2;   // cvt_pkrtz return type
typedef __attribute__((ext_vector_type(4))) float f32x4;

#define B_SZ  2
#define L_SEQ 1024
#define D_EMB 768
#define KF    16
#define MDIM  (B_SZ * L_SEQ)   // 2048 GEMM rows
#define KROW  (KF * D_EMB)     // 12288 per-row A length

// ---- async global->LDS, 16B per lane (linear LDS dest: wave base + lane*16) ----
__device__ __forceinline__ void gload16(const void* g, void* l) {
    __builtin_amdgcn_global_load_lds(
        (const __attribute__((address_space(1))) u32*)g,
        (__attribute__((address_space(3))) u32*)l, 16, 0, 0);
}

// =====================================================================
// Stage 1: causal conv.  U_plus[b,t,k,d] = sum_{s=0..t} phi[s,k] x[b,t-s,d]
//          U_minus same with (-1)^s phi[s,k].  Output fp16 (MFMA A-operand).
// Block: 64 t x 64 d tile for one (b,k).
// =====================================================================
__global__ __launch_bounds__(256) void stu_conv(const float* __restrict__ x,
                                                const float* __restrict__ phi,
                                                u16* __restrict__ Up,
                                                u16* __restrict__ Um) {
    __shared__ __align__(16) float xs[64][68];
    __shared__ float php[128];
    __shared__ float phm[128];

    const int t0 = blockIdx.x << 6;
    const int b  = blockIdx.y >> 4;
    const int k  = blockIdx.y & 15;
    const int d0 = blockIdx.z << 6;
    const int tid = threadIdx.x;
    const int tg = tid >> 2;          // 0..63 : t row within tile
    const int dg = (tid & 3) << 4;    // 0,16,32,48 : d sub-block

    float accp[16], accm[16];
#pragma unroll
    for (int i = 0; i < 16; ++i) { accp[i] = 0.f; accm[i] = 0.f; }

    const float* xb = x + (size_t)b * L_SEQ * D_EMB + d0;

    for (int r0 = 0; r0 <= t0; r0 += 64) {
        __syncthreads();
#pragma unroll
        for (int j = 0; j < 4; ++j) {
            int c   = tid + (j << 8);
            int row = c >> 4;
            int col = (c & 15) << 2;
            *(float4*)&xs[row][col] =
                *(const float4*)&xb[(size_t)(r0 + row) * D_EMB + col];
        }
        if (tid < 128) {
            int s = t0 - r0 - 63 + tid;
            float v = (s >= 0 && s < L_SEQ) ? phi[s * KF + k] : 0.f;
            php[tid] = v;
            phm[tid] = (s & 1) ? -v : v;
        }
        __syncthreads();

#pragma unroll 4
        for (int rr = 0; rr < 64; ++rr) {
            const int j = 63 + tg - rr;
            const float p = php[j];
            const float m = phm[j];
#pragma unroll
            for (int q = 0; q < 4; ++q) {
                const float4 xv = *(const float4*)&xs[rr][dg + (q << 2)];
                accp[q*4+0] += p * xv.x; accp[q*4+1] += p * xv.y;
                accp[q*4+2] += p * xv.z; accp[q*4+3] += p * xv.w;
                accm[q*4+0] += m * xv.x; accm[q*4+1] += m * xv.y;
                accm[q*4+2] += m * xv.z; accm[q*4+3] += m * xv.w;
            }
        }
    }

    const int t = t0 + tg;
    size_t base = (((size_t)(b * L_SEQ + t)) * KF + k) * D_EMB + d0 + dg;
    u16 bp[16], bm[16];
#pragma unroll
    for (int i = 0; i < 16; ++i) {
        bp[i] = __half_as_ushort(__float2half(accp[i]));
        bm[i] = __half_as_ushort(__float2half(accm[i]));
    }
    *(uint4*)&Up[base]     = *(uint4*)&bp[0];
    *(uint4*)&Up[base + 8] = *(uint4*)&bp[8];
    *(uint4*)&Um[base]     = *(uint4*)&bm[0];
    *(uint4*)&Um[base + 8] = *(uint4*)&bm[8];
}

// =====================================================================
// Stage 2 (MFMA): out[m,o] += sum_{k,i} U[m,(k,i)] * M[k,o,i]  for both signs.
// A = U fp16 row-major [2048][12288]; B^T = M[k][o][i] (K-contiguous per k).
// 128x128 C-tile, BK=32, 4 waves x (4x4 frags of 16x16x32 f16 MFMA).
// A staged via global_load_lds (linear LDS); B reg-staged fp32->f16 (cvt_pkrtz).
// grid.z = 8 : sign (bit0) x k-quarter -> f32 atomicAdd combine.
// =====================================================================
__global__ __launch_bounds__(256) void stu_spectral_mfma(
        const u16* __restrict__ Up, const u16* __restrict__ Um,
        const float* __restrict__ Mp, const float* __restrict__ Mm,
        float* __restrict__ out) {
    __shared__ __align__(16) u16 As[128 * 32];
    __shared__ __align__(16) u16 Bs[128 * 32];

    const int m0 = blockIdx.x << 7;
    const int o0 = blockIdx.y << 7;
    const int z  = blockIdx.z;
    const int sign = z & 1;
    const int k0 = (z >> 1) << 2;                 // 0,4,8,12

    const u16*   A    = sign ? Um : Up;
    const float* Bsrc = sign ? Mm : Mp;

    const int tid  = threadIdx.x;
    const int lane = tid & 63;
    const int wid  = tid >> 6;
    const int wr   = wid >> 1;                    // wave row 0..1
    const int wc   = wid & 1;                     // wave col 0..1
    const int lr   = lane & 15;
    const int lk   = lane >> 4;                   // k-chunk 0..3

    const int brow = tid >> 1;                    // B stage: row 0..127
    const int bcol = (tid & 1) << 4;              // 0 or 16 (f32 elems)

    f32x4 acc[4][4];
#pragma unroll
    for (int m = 0; m < 4; ++m)
#pragma unroll
        for (int n = 0; n < 4; ++n)
            acc[m][n] = (f32x4){0.f, 0.f, 0.f, 0.f};

    for (int k = k0; k < k0 + 4; ++k) {
        const u16*   Ak = A + (size_t)m0 * KROW + k * D_EMB;
        const float* Bk = Bsrc + (size_t)k * D_EMB * D_EMB + (size_t)o0 * D_EMB;

        for (int ic = 0; ic < D_EMB; ic += 32) {
            __syncthreads();
            // ---- stage A: 128x32 f16 via 2x global_load_lds (16B/lane) ----
            {
                const int c0 = tid, c1 = 256 + tid;
                gload16(Ak + (size_t)(c0 >> 2) * KROW + ic + ((c0 & 3) << 3),
                        &As[c0 << 3]);
                gload16(Ak + (size_t)(c1 >> 2) * KROW + ic + ((c1 & 3) << 3),
                        &As[c1 << 3]);
            }
            // ---- stage B: 128x32, fp32 -> f16 in regs -> ds_write_b128 ----
            {
                const float* g = Bk + (size_t)brow * D_EMB + ic + bcol;
                const float4 v0 = *(const float4*)g;
                const float4 v1 = *(const float4*)(g + 4);
                const float4 v2 = *(const float4*)(g + 8);
                const float4 v3 = *(const float4*)(g + 12);
                union { fp16x2 h2[8]; uint4 q[2]; } u;
                u.h2[0] = __builtin_amdgcn_cvt_pkrtz(v0.x, v0.y);
                u.h2[1] = __builtin_amdgcn_cvt_pkrtz(v0.z, v0.w);
                u.h2[2] = __builtin_amdgcn_cvt_pkrtz(v1.x, v1.y);
                u.h2[3] = __builtin_amdgcn_cvt_pkrtz(v1.z, v1.w);
                u.h2[4] = __builtin_amdgcn_cvt_pkrtz(v2.x, v2.y);
                u.h2[5] = __builtin_amdgcn_cvt_pkrtz(v2.z, v2.w);
                u.h2[6] = __builtin_amdgcn_cvt_pkrtz(v3.x, v3.y);
                u.h2[7] = __builtin_amdgcn_cvt_pkrtz(v3.z, v3.w);
                *(uint4*)&Bs[brow * 32 + bcol]     = u.q[0];
                *(uint4*)&Bs[brow * 32 + bcol + 8] = u.q[1];
            }
            __syncthreads();

            f16x8 af[4], bf[4];
#pragma unroll
            for (int m = 0; m < 4; ++m)
                af[m] = *(const f16x8*)&As[(wr * 64 + m * 16 + lr) * 32 + lk * 8];
#pragma unroll
            for (int n = 0; n < 4; ++n)
                bf[n] = *(const f16x8*)&Bs[(wc * 64 + n * 16 + lr) * 32 + lk * 8];
#pragma unroll
            for (int m = 0; m < 4; ++m)
#pragma unroll
                for (int n = 0; n < 4; ++n)
                    acc[m][n] = __builtin_amdgcn_mfma_f32_16x16x32_f16(
                        af[m], bf[n], acc[m][n], 0, 0, 0);
        }
    }

    // epilogue: C row = m*16 + lk*4 + j, col = n*16 + lr  (verified m89 mapping)
#pragma unroll
    for (int m = 0; m < 4; ++m) {
        const int row = m0 + wr * 64 + m * 16 + lk * 4;
#pragma unroll
        for (int n = 0; n < 4; ++n) {
            const int col = o0 + wc * 64 + n * 16 + lr;
#pragma unroll
            for (int j = 0; j < 4; ++j)
                atomicAdd(&out[(size_t)(row + j) * D_EMB + col], acc[m][n][j]);
        }
    }
}

extern "C" void kernel_launch(void* const* d_in, const int* in_sizes, int n_in,
                              void* d_out, int out_size, void* d_ws, size_t ws_size,
                              hipStream_t stream) {
    const float* x   = (const float*)d_in[0];
    const float* phi = (const float*)d_in[1];
    const float* Mp  = (const float*)d_in[2];
    const float* Mm  = (const float*)d_in[3];
    float* out = (float*)d_out;

    const size_t S = (size_t)MDIM * KROW;        // 25,165,824 elems
    u16* Up = (u16*)d_ws;
    u16* Um = Up + S;                            // ~101 MB of ws total

    (void)hipMemsetAsync(d_out, 0, (size_t)out_size * sizeof(float), stream);

    dim3 g1(L_SEQ / 64, B_SZ * KF, D_EMB / 64);  // 16 x 32 x 12
    stu_conv<<<g1, dim3(256), 0, stream>>>(x, phi, Up, Um);

    dim3 g2(MDIM / 128, D_EMB / 128, 8);         // 16 x 6 x 8 = 768 blocks
    stu_spectral_mfma<<<g2, dim3(256), 0, stream>>>(Up, Um, Mp, Mm, out);
}

// Round 4
// 283.791 us; speedup vs baseline: 9.3474x; 3.9381x over previous
//
#include <hip/hip_runtime.h>
#include <hip/hip_fp16.h>

typedef unsigned short u16;
typedef unsigned int   u32;
typedef _Float16 f16;
typedef __attribute__((ext_vector_type(8))) f16 f16x8;
typedef __attribute__((ext_vector_type(2))) __fp16 fp16x2;   // cvt_pkrtz return type
typedef __attribute__((ext_vector_type(4))) float f32x4;

#define B_SZ  2
#define L_SEQ 1024
#define D_EMB 768
#define KF    16
#define MDIM  (B_SZ * L_SEQ)   // 2048 GEMM rows
#define KROW  (KF * D_EMB)     // 12288 per-row A length

// ---- async global->LDS, 16B per lane (linear LDS dest: wave base + lane*16) ----
__device__ __forceinline__ void gload16(const void* g, void* l) {
    __builtin_amdgcn_global_load_lds(
        (const __attribute__((address_space(1))) u32*)g,
        (__attribute__((address_space(3))) u32*)l, 16, 0, 0);
}

// =====================================================================
// Setup A: x [b][s][d] f32  ->  xT [b][d][s] f16, PRE-SWIZZLED within each
// 64-elem s-chunk: elem stored at (s&~63) + ((s&63) ^ ((d&7)<<3)).
// So conv's linear global_load_lds lands the tile swizzled in LDS.
// =====================================================================
__global__ __launch_bounds__(256) void stu_xt(const float* __restrict__ x,
                                              u16* __restrict__ xT) {
    __shared__ __align__(16) float xs[64][68];
    const int s0 = blockIdx.x << 6;
    const int d0 = blockIdx.y << 6;
    const int b  = blockIdx.z;
    const int tid = threadIdx.x;

#pragma unroll
    for (int j = 0; j < 4; ++j) {
        int c = tid + (j << 8);
        int row = c >> 4;
        int col = (c & 15) << 2;
        *(float4*)&xs[row][col] =
            *(const float4*)&x[((size_t)b * L_SEQ + s0 + row) * D_EMB + d0 + col];
    }
    __syncthreads();

    const int dl = tid >> 2;          // 0..63 local d
    const int ss = (tid & 3) << 4;    // 0,16,32,48
    const int dg = d0 + dl;
    const int xorv = (dg & 7) << 3;

    union { u16 v[16]; uint4 q[2]; } pk;
#pragma unroll
    for (int u = 0; u < 16; ++u)
        pk.v[u] = __half_as_ushort(__float2half(xs[ss + u][dl]));

    size_t base = (size_t)b * D_EMB * L_SEQ + (size_t)dg * L_SEQ + s0;
    *(uint4*)&xT[base + ( ss      ^ xorv)] = pk.q[0];
    *(uint4*)&xT[base + ((ss + 8) ^ xorv)] = pk.q[1];
}

// =====================================================================
// Setup B: Toeplitz tile table. Ttab[sign][k][q] = 64x64 f16 tile
// T[tt][ss] = (+/-1)^s * phi[s,k],  s = 64q + tt - ss  (0 if out of range).
// Stored pre-swizzled: idx = tt*64 + (ss ^ ((tt&7)<<3)).
// =====================================================================
__global__ __launch_bounds__(256) void stu_ttab(const float* __restrict__ phi,
                                                u16* __restrict__ Ttab) {
    const int q    = blockIdx.x;      // 0..15  (t0-r0)/64
    const int k    = blockIdx.y;      // 0..15
    const int sign = blockIdx.z;      // 0..1
    const int tid  = threadIdx.x;
    const int tt   = tid >> 2;        // 0..63
    const int ss0  = (tid & 3) << 4;  // 0,16,32,48

    union { u16 v[16]; uint4 q4[2]; } pk;
#pragma unroll
    for (int u = 0; u < 16; ++u) {
        int s = (q << 6) + tt - (ss0 + u);
        float v = (s >= 0 && s < L_SEQ) ? phi[s * KF + k] : 0.f;
        if (sign && (s & 1)) v = -v;
        pk.v[u] = __half_as_ushort(__float2half(v));
    }
    const int xorv = (tt & 7) << 3;
    u16* tile = Ttab + (((size_t)(sign * KF + k) * 16 + q) << 12);
    *(uint4*)&tile[(tt << 6) + ( ss0      ^ xorv)] = pk.q4[0];
    *(uint4*)&tile[(tt << 6) + ((ss0 + 8) ^ xorv)] = pk.q4[1];
}

// =====================================================================
// Stage 1 (MFMA): per (t-tile, b, k, d-tile): C[64 t][128 d] for BOTH signs.
// A = Toeplitz tile (64x64, from Ttab), B = xT tile (128 d x 64 s).
// s-loop r0 = 0..t0 step 64 (triangular block skip). 2-barrier m97 loop.
// LDS rows are 128B; reads XOR-swizzled (sources pre-swizzled -> gload linear).
// =====================================================================
__global__ __launch_bounds__(256) void stu_conv_mfma(const u16* __restrict__ xT,
                                                     const u16* __restrict__ Ttab,
                                                     u16* __restrict__ Up,
                                                     u16* __restrict__ Um) {
    __shared__ __align__(16) u16 Xs[128 * 64];   // [d=128][s=64]
    __shared__ __align__(16) u16 Tp[64 * 64];    // [t=64][s=64]
    __shared__ __align__(16) u16 Tm[64 * 64];

    const int ti = blockIdx.x;
    const int t0 = ti << 6;
    const int b  = blockIdx.y >> 4;
    const int k  = blockIdx.y & 15;
    const int d0 = blockIdx.z << 7;

    const int tid  = threadIdx.x;
    const int lane = tid & 63;
    const int wid  = tid >> 6;
    const int wr   = wid >> 1;        // t-half (32 rows)
    const int wc   = wid & 1;         // d-half (64 cols)
    const int lr   = lane & 15;
    const int lk   = lane >> 4;

    f32x4 acc[2][2][4];               // [sign][m][n]
#pragma unroll
    for (int s = 0; s < 2; ++s)
#pragma unroll
        for (int m = 0; m < 2; ++m)
#pragma unroll
            for (int n = 0; n < 4; ++n)
                acc[s][m][n] = (f32x4){0.f, 0.f, 0.f, 0.f};

    const u16* xTb = xT + (size_t)b * D_EMB * L_SEQ + (size_t)d0 * L_SEQ;
    const u16* Tpk = Ttab + ((size_t)k * 16) * 4096;
    const u16* Tmk = Ttab + ((size_t)(KF + k) * 16) * 4096;

    for (int r0 = 0; r0 <= t0; r0 += 64) {
        const int q = (t0 - r0) >> 6;
        __syncthreads();
        // ---- stage xT tile: 128 rows x 128B = 1024 chunks ----
#pragma unroll
        for (int j = 0; j < 4; ++j) {
            int c = tid + (j << 8);
            gload16(xTb + (size_t)(c >> 3) * L_SEQ + r0 + ((c & 7) << 3),
                    &Xs[c << 3]);
        }
        // ---- stage Toeplitz tiles: 512 chunks each ----
        {
            const u16* tp = Tpk + ((size_t)q << 12);
            const u16* tm = Tmk + ((size_t)q << 12);
            gload16(tp + (tid << 3),         &Tp[tid << 3]);
            gload16(tp + ((tid + 256) << 3), &Tp[(tid + 256) << 3]);
            gload16(tm + (tid << 3),         &Tm[tid << 3]);
            gload16(tm + ((tid + 256) << 3), &Tm[(tid + 256) << 3]);
        }
        __syncthreads();

#pragma unroll
        for (int kk = 0; kk < 2; ++kk) {
            f16x8 bfr[4];
#pragma unroll
            for (int n = 0; n < 4; ++n) {
                const int row = (wc << 6) + (n << 4) + lr;
                const int boff = ((kk << 6) + (lk << 4)) ^ ((row & 7) << 4);
                bfr[n] = *(const f16x8*)((const char*)&Xs[0] + row * 128 + boff);
            }
#pragma unroll
            for (int m = 0; m < 2; ++m) {
                const int rowt = (wr << 5) + (m << 4) + lr;
                const int aoff = ((kk << 6) + (lk << 4)) ^ ((rowt & 7) << 4);
                const f16x8 afp = *(const f16x8*)((const char*)&Tp[0] + rowt * 128 + aoff);
                const f16x8 afm = *(const f16x8*)((const char*)&Tm[0] + rowt * 128 + aoff);
#pragma unroll
                for (int n = 0; n < 4; ++n) {
                    acc[0][m][n] = __builtin_amdgcn_mfma_f32_16x16x32_f16(
                        afp, bfr[n], acc[0][m][n], 0, 0, 0);
                    acc[1][m][n] = __builtin_amdgcn_mfma_f32_16x16x32_f16(
                        afm, bfr[n], acc[1][m][n], 0, 0, 0);
                }
            }
        }
    }

    // epilogue: D row (t) = m*16 + lk*4 + j, col (d) = n*16 + lr
#pragma unroll
    for (int m = 0; m < 2; ++m) {
        const int trow = t0 + (wr << 5) + (m << 4) + (lk << 2);
#pragma unroll
        for (int n = 0; n < 4; ++n) {
            const int col = d0 + (wc << 6) + (n << 4) + lr;
#pragma unroll
            for (int j = 0; j < 4; ++j) {
                size_t idx = ((size_t)(b * L_SEQ + trow + j) * KF + k) * D_EMB + col;
                Up[idx] = __half_as_ushort(__float2half(acc[0][m][n][j]));
                Um[idx] = __half_as_ushort(__float2half(acc[1][m][n][j]));
            }
        }
    }
}

// =====================================================================
// Stage 2 (MFMA): out[m,o] += sum_{k,i} U[m,(k,i)] * M[k,o,i]  (both signs).
// Unchanged from round 3 (verified).
// =====================================================================
__global__ __launch_bounds__(256) void stu_spectral_mfma(
        const u16* __restrict__ Up, const u16* __restrict__ Um,
        const float* __restrict__ Mp, const float* __restrict__ Mm,
        float* __restrict__ out) {
    __shared__ __align__(16) u16 As[128 * 32];
    __shared__ __align__(16) u16 Bs[128 * 32];

    const int m0 = blockIdx.x << 7;
    const int o0 = blockIdx.y << 7;
    const int z  = blockIdx.z;
    const int sign = z & 1;
    const int k0 = (z >> 1) << 2;

    const u16*   A    = sign ? Um : Up;
    const float* Bsrc = sign ? Mm : Mp;

    const int tid  = threadIdx.x;
    const int lane = tid & 63;
    const int wid  = tid >> 6;
    const int wr   = wid >> 1;
    const int wc   = wid & 1;
    const int lr   = lane & 15;
    const int lk   = lane >> 4;

    const int brow = tid >> 1;
    const int bcol = (tid & 1) << 4;

    f32x4 acc[4][4];
#pragma unroll
    for (int m = 0; m < 4; ++m)
#pragma unroll
        for (int n = 0; n < 4; ++n)
            acc[m][n] = (f32x4){0.f, 0.f, 0.f, 0.f};

    for (int k = k0; k < k0 + 4; ++k) {
        const u16*   Ak = A + (size_t)m0 * KROW + k * D_EMB;
        const float* Bk = Bsrc + (size_t)k * D_EMB * D_EMB + (size_t)o0 * D_EMB;

        for (int ic = 0; ic < D_EMB; ic += 32) {
            __syncthreads();
            {
                const int c0 = tid, c1 = 256 + tid;
                gload16(Ak + (size_t)(c0 >> 2) * KROW + ic + ((c0 & 3) << 3),
                        &As[c0 << 3]);
                gload16(Ak + (size_t)(c1 >> 2) * KROW + ic + ((c1 & 3) << 3),
                        &As[c1 << 3]);
            }
            {
                const float* g = Bk + (size_t)brow * D_EMB + ic + bcol;
                const float4 v0 = *(const float4*)g;
                const float4 v1 = *(const float4*)(g + 4);
                const float4 v2 = *(const float4*)(g + 8);
                const float4 v3 = *(const float4*)(g + 12);
                union { fp16x2 h2[8]; uint4 q[2]; } u;
                u.h2[0] = __builtin_amdgcn_cvt_pkrtz(v0.x, v0.y);
                u.h2[1] = __builtin_amdgcn_cvt_pkrtz(v0.z, v0.w);
                u.h2[2] = __builtin_amdgcn_cvt_pkrtz(v1.x, v1.y);
                u.h2[3] = __builtin_amdgcn_cvt_pkrtz(v1.z, v1.w);
                u.h2[4] = __builtin_amdgcn_cvt_pkrtz(v2.x, v2.y);
                u.h2[5] = __builtin_amdgcn_cvt_pkrtz(v2.z, v2.w);
                u.h2[6] = __builtin_amdgcn_cvt_pkrtz(v3.x, v3.y);
                u.h2[7] = __builtin_amdgcn_cvt_pkrtz(v3.z, v3.w);
                *(uint4*)&Bs[brow * 32 + bcol]     = u.q[0];
                *(uint4*)&Bs[brow * 32 + bcol + 8] = u.q[1];
            }
            __syncthreads();

            f16x8 af[4], bf[4];
#pragma unroll
            for (int m = 0; m < 4; ++m)
                af[m] = *(const f16x8*)&As[(wr * 64 + m * 16 + lr) * 32 + lk * 8];
#pragma unroll
            for (int n = 0; n < 4; ++n)
                bf[n] = *(const f16x8*)&Bs[(wc * 64 + n * 16 + lr) * 32 + lk * 8];
#pragma unroll
            for (int m = 0; m < 4; ++m)
#pragma unroll
                for (int n = 0; n < 4; ++n)
                    acc[m][n] = __builtin_amdgcn_mfma_f32_16x16x32_f16(
                        af[m], bf[n], acc[m][n], 0, 0, 0);
        }
    }

#pragma unroll
    for (int m = 0; m < 4; ++m) {
        const int row = m0 + wr * 64 + m * 16 + lk * 4;
#pragma unroll
        for (int n = 0; n < 4; ++n) {
            const int col = o0 + wc * 64 + n * 16 + lr;
#pragma unroll
            for (int j = 0; j < 4; ++j)
                atomicAdd(&out[(size_t)(row + j) * D_EMB + col], acc[m][n][j]);
        }
    }
}

extern "C" void kernel_launch(void* const* d_in, const int* in_sizes, int n_in,
                              void* d_out, int out_size, void* d_ws, size_t ws_size,
                              hipStream_t stream) {
    const float* x   = (const float*)d_in[0];
    const float* phi = (const float*)d_in[1];
    const float* Mp  = (const float*)d_in[2];
    const float* Mm  = (const float*)d_in[3];
    float* out = (float*)d_out;

    const size_t S = (size_t)MDIM * KROW;            // 25,165,824 elems
    u16* Up   = (u16*)d_ws;
    u16* Um   = Up + S;
    u16* xT   = Um + S;                              // 2*768*1024 = 1,572,864
    u16* Ttab = xT + (size_t)B_SZ * D_EMB * L_SEQ;   // 2*16*16*4096 = 2,097,152

    (void)hipMemsetAsync(d_out, 0, (size_t)out_size * sizeof(float), stream);

    stu_xt  <<<dim3(L_SEQ / 64, D_EMB / 64, B_SZ), dim3(256), 0, stream>>>(x, xT);
    stu_ttab<<<dim3(16, KF, 2),                    dim3(256), 0, stream>>>(phi, Ttab);

    dim3 g1(L_SEQ / 64, B_SZ * KF, D_EMB / 128);     // 16 x 32 x 6 = 3072
    stu_conv_mfma<<<g1, dim3(256), 0, stream>>>(xT, Ttab, Up, Um);

    dim3 g2(MDIM / 128, D_EMB / 128, 8);             // 16 x 6 x 8 = 768
    stu_spectral_mfma<<<g2, dim3(256), 0, stream>>>(Up, Um, Mp, Mm, out);
}

// Round 5
// 251.178 us; speedup vs baseline: 10.5611x; 1.1298x over previous
//
#include <hip/hip_runtime.h>
#include <hip/hip_fp16.h>

typedef unsigned short u16;
typedef unsigned int   u32;
typedef _Float16 f16;
typedef __attribute__((ext_vector_type(8))) f16 f16x8;
typedef __attribute__((ext_vector_type(2))) __fp16 fp16x2;   // cvt_pkrtz return type
typedef __attribute__((ext_vector_type(4))) float f32x4;

#define B_SZ  2
#define L_SEQ 1024
#define D_EMB 768
#define KF    16
#define MDIM  (B_SZ * L_SEQ)   // 2048 GEMM rows
#define KROW  (KF * D_EMB)     // 12288 per-row A length
#define MELEM ((size_t)KF * D_EMB * D_EMB)   // 9,437,184 per M matrix

// ---- async global->LDS, 16B per lane (linear LDS dest: wave base + lane*16) ----
__device__ __forceinline__ void gload16(const void* g, void* l) {
    __builtin_amdgcn_global_load_lds(
        (const __attribute__((address_space(1))) u32*)g,
        (__attribute__((address_space(3))) u32*)l, 16, 0, 0);
}

// =====================================================================
// Setup M: Mp/Mm f32 -> fp16 (halves stage-2 B traffic; enables gload-B).
// =====================================================================
__global__ __launch_bounds__(256) void stu_mcvt(const float* __restrict__ Mp,
                                                const float* __restrict__ Mm,
                                                u16* __restrict__ Hp,
                                                u16* __restrict__ Hm) {
    const size_t n8 = MELEM / 8;                 // 1,179,648 chunks
    size_t i = (size_t)blockIdx.x * 256 + threadIdx.x;
    const size_t stride = (size_t)gridDim.x * 256;
    for (size_t c = i; c < n8; c += stride) {
        const size_t g = c << 3;
        {
            const float4 a0 = *(const float4*)&Mp[g];
            const float4 a1 = *(const float4*)&Mp[g + 4];
            union { fp16x2 h2[4]; uint4 q; } u;
            u.h2[0] = __builtin_amdgcn_cvt_pkrtz(a0.x, a0.y);
            u.h2[1] = __builtin_amdgcn_cvt_pkrtz(a0.z, a0.w);
            u.h2[2] = __builtin_amdgcn_cvt_pkrtz(a1.x, a1.y);
            u.h2[3] = __builtin_amdgcn_cvt_pkrtz(a1.z, a1.w);
            *(uint4*)&Hp[g] = u.q;
        }
        {
            const float4 a0 = *(const float4*)&Mm[g];
            const float4 a1 = *(const float4*)&Mm[g + 4];
            union { fp16x2 h2[4]; uint4 q; } u;
            u.h2[0] = __builtin_amdgcn_cvt_pkrtz(a0.x, a0.y);
            u.h2[1] = __builtin_amdgcn_cvt_pkrtz(a0.z, a0.w);
            u.h2[2] = __builtin_amdgcn_cvt_pkrtz(a1.x, a1.y);
            u.h2[3] = __builtin_amdgcn_cvt_pkrtz(a1.z, a1.w);
            *(uint4*)&Hm[g] = u.q;
        }
    }
}

// =====================================================================
// Setup A: x [b][s][d] f32  ->  xT [b][d][s] f16, PRE-SWIZZLED within each
// 64-elem s-chunk: elem stored at (s&~63) + ((s&63) ^ ((d&7)<<3)).
// =====================================================================
__global__ __launch_bounds__(256) void stu_xt(const float* __restrict__ x,
                                              u16* __restrict__ xT) {
    __shared__ __align__(16) float xs[64][68];
    const int s0 = blockIdx.x << 6;
    const int d0 = blockIdx.y << 6;
    const int b  = blockIdx.z;
    const int tid = threadIdx.x;

#pragma unroll
    for (int j = 0; j < 4; ++j) {
        int c = tid + (j << 8);
        int row = c >> 4;
        int col = (c & 15) << 2;
        *(float4*)&xs[row][col] =
            *(const float4*)&x[((size_t)b * L_SEQ + s0 + row) * D_EMB + d0 + col];
    }
    __syncthreads();

    const int dl = tid >> 2;
    const int ss = (tid & 3) << 4;
    const int dg = d0 + dl;
    const int xorv = (dg & 7) << 3;

    union { u16 v[16]; uint4 q[2]; } pk;
#pragma unroll
    for (int u = 0; u < 16; ++u)
        pk.v[u] = __half_as_ushort(__float2half(xs[ss + u][dl]));

    size_t base = (size_t)b * D_EMB * L_SEQ + (size_t)dg * L_SEQ + s0;
    *(uint4*)&xT[base + ( ss      ^ xorv)] = pk.q[0];
    *(uint4*)&xT[base + ((ss + 8) ^ xorv)] = pk.q[1];
}

// =====================================================================
// Setup B: Toeplitz tile table (pre-swizzled), as round 4.
// =====================================================================
__global__ __launch_bounds__(256) void stu_ttab(const float* __restrict__ phi,
                                                u16* __restrict__ Ttab) {
    const int q    = blockIdx.x;
    const int k    = blockIdx.y;
    const int sign = blockIdx.z;
    const int tid  = threadIdx.x;
    const int tt   = tid >> 2;
    const int ss0  = (tid & 3) << 4;

    union { u16 v[16]; uint4 q4[2]; } pk;
#pragma unroll
    for (int u = 0; u < 16; ++u) {
        int s = (q << 6) + tt - (ss0 + u);
        float v = (s >= 0 && s < L_SEQ) ? phi[s * KF + k] : 0.f;
        if (sign && (s & 1)) v = -v;
        pk.v[u] = __half_as_ushort(__float2half(v));
    }
    const int xorv = (tt & 7) << 3;
    u16* tile = Ttab + (((size_t)(sign * KF + k) * 16 + q) << 12);
    *(uint4*)&tile[(tt << 6) + ( ss0      ^ xorv)] = pk.q4[0];
    *(uint4*)&tile[(tt << 6) + ((ss0 + 8) ^ xorv)] = pk.q4[1];
}

// =====================================================================
// Stage 1 (MFMA conv): unchanged from round 4 (verified).
// =====================================================================
__global__ __launch_bounds__(256) void stu_conv_mfma(const u16* __restrict__ xT,
                                                     const u16* __restrict__ Ttab,
                                                     u16* __restrict__ Up,
                                                     u16* __restrict__ Um) {
    __shared__ __align__(16) u16 Xs[128 * 64];
    __shared__ __align__(16) u16 Tp[64 * 64];
    __shared__ __align__(16) u16 Tm[64 * 64];

    const int ti = blockIdx.x;
    const int t0 = ti << 6;
    const int b  = blockIdx.y >> 4;
    const int k  = blockIdx.y & 15;
    const int d0 = blockIdx.z << 7;

    const int tid  = threadIdx.x;
    const int lane = tid & 63;
    const int wid  = tid >> 6;
    const int wr   = wid >> 1;
    const int wc   = wid & 1;
    const int lr   = lane & 15;
    const int lk   = lane >> 4;

    f32x4 acc[2][2][4];
#pragma unroll
    for (int s = 0; s < 2; ++s)
#pragma unroll
        for (int m = 0; m < 2; ++m)
#pragma unroll
            for (int n = 0; n < 4; ++n)
                acc[s][m][n] = (f32x4){0.f, 0.f, 0.f, 0.f};

    const u16* xTb = xT + (size_t)b * D_EMB * L_SEQ + (size_t)d0 * L_SEQ;
    const u16* Tpk = Ttab + ((size_t)k * 16) * 4096;
    const u16* Tmk = Ttab + ((size_t)(KF + k) * 16) * 4096;

    for (int r0 = 0; r0 <= t0; r0 += 64) {
        const int q = (t0 - r0) >> 6;
        __syncthreads();
#pragma unroll
        for (int j = 0; j < 4; ++j) {
            int c = tid + (j << 8);
            gload16(xTb + (size_t)(c >> 3) * L_SEQ + r0 + ((c & 7) << 3),
                    &Xs[c << 3]);
        }
        {
            const u16* tp = Tpk + ((size_t)q << 12);
            const u16* tm = Tmk + ((size_t)q << 12);
            gload16(tp + (tid << 3),         &Tp[tid << 3]);
            gload16(tp + ((tid + 256) << 3), &Tp[(tid + 256) << 3]);
            gload16(tm + (tid << 3),         &Tm[tid << 3]);
            gload16(tm + ((tid + 256) << 3), &Tm[(tid + 256) << 3]);
        }
        __syncthreads();

#pragma unroll
        for (int kk = 0; kk < 2; ++kk) {
            f16x8 bfr[4];
#pragma unroll
            for (int n = 0; n < 4; ++n) {
                const int row = (wc << 6) + (n << 4) + lr;
                const int boff = ((kk << 6) + (lk << 4)) ^ ((row & 7) << 4);
                bfr[n] = *(const f16x8*)((const char*)&Xs[0] + row * 128 + boff);
            }
#pragma unroll
            for (int m = 0; m < 2; ++m) {
                const int rowt = (wr << 5) + (m << 4) + lr;
                const int aoff = ((kk << 6) + (lk << 4)) ^ ((rowt & 7) << 4);
                const f16x8 afp = *(const f16x8*)((const char*)&Tp[0] + rowt * 128 + aoff);
                const f16x8 afm = *(const f16x8*)((const char*)&Tm[0] + rowt * 128 + aoff);
#pragma unroll
                for (int n = 0; n < 4; ++n) {
                    acc[0][m][n] = __builtin_amdgcn_mfma_f32_16x16x32_f16(
                        afp, bfr[n], acc[0][m][n], 0, 0, 0);
                    acc[1][m][n] = __builtin_amdgcn_mfma_f32_16x16x32_f16(
                        afm, bfr[n], acc[1][m][n], 0, 0, 0);
                }
            }
        }
    }

#pragma unroll
    for (int m = 0; m < 2; ++m) {
        const int trow = t0 + (wr << 5) + (m << 4) + (lk << 2);
#pragma unroll
        for (int n = 0; n < 4; ++n) {
            const int col = d0 + (wc << 6) + (n << 4) + lr;
#pragma unroll
            for (int j = 0; j < 4; ++j) {
                size_t idx = ((size_t)(b * L_SEQ + trow + j) * KF + k) * D_EMB + col;
                Up[idx] = __half_as_ushort(__float2half(acc[0][m][n][j]));
                Um[idx] = __half_as_ushort(__float2half(acc[1][m][n][j]));
            }
        }
    }
}

// =====================================================================
// Stage 2 (MFMA): both operands fp16, both staged via global_load_lds.
// 1D grid 768, XCD-partitioned: z = h&7 (one z-slice per XCD, disjoint
// 22 MB working set), o fastest within slice (A-panel sharing).
// =====================================================================
__global__ __launch_bounds__(256) void stu_spectral_mfma(
        const u16* __restrict__ Up, const u16* __restrict__ Um,
        const u16* __restrict__ Mhp, const u16* __restrict__ Mhm,
        float* __restrict__ out) {
    __shared__ __align__(16) u16 As[128 * 32];
    __shared__ __align__(16) u16 Bs[128 * 32];

    const int h   = blockIdx.x;
    const int z   = h & 7;                        // XCD slice
    const int rem = h >> 3;                       // 0..95
    const int o0  = (rem % 6) << 7;
    const int m0  = (rem / 6) << 7;
    const int sign = z & 1;
    const int k0 = (z >> 1) << 2;

    const u16* A    = sign ? Um : Up;
    const u16* Bsrc = sign ? Mhm : Mhp;

    const int tid  = threadIdx.x;
    const int lane = tid & 63;
    const int wid  = tid >> 6;
    const int wr   = wid >> 1;
    const int wc   = wid & 1;
    const int lr   = lane & 15;
    const int lk   = lane >> 4;

    f32x4 acc[4][4];
#pragma unroll
    for (int m = 0; m < 4; ++m)
#pragma unroll
        for (int n = 0; n < 4; ++n)
            acc[m][n] = (f32x4){0.f, 0.f, 0.f, 0.f};

    for (int k = k0; k < k0 + 4; ++k) {
        const u16* Ak = A + (size_t)m0 * KROW + k * D_EMB;
        const u16* Bk = Bsrc + (size_t)k * D_EMB * D_EMB + (size_t)o0 * D_EMB;

        for (int ic = 0; ic < D_EMB; ic += 32) {
            __syncthreads();
            // ---- stage A: 128x32 f16, 2 gloads ----
            {
                const int c0 = tid, c1 = 256 + tid;
                gload16(Ak + (size_t)(c0 >> 2) * KROW + ic + ((c0 & 3) << 3),
                        &As[c0 << 3]);
                gload16(Ak + (size_t)(c1 >> 2) * KROW + ic + ((c1 & 3) << 3),
                        &As[c1 << 3]);
            }
            // ---- stage B: 128x32 f16, 2 gloads (row stride D_EMB) ----
            {
                const int c0 = tid, c1 = 256 + tid;
                gload16(Bk + (size_t)(c0 >> 2) * D_EMB + ic + ((c0 & 3) << 3),
                        &Bs[c0 << 3]);
                gload16(Bk + (size_t)(c1 >> 2) * D_EMB + ic + ((c1 & 3) << 3),
                        &Bs[c1 << 3]);
            }
            __syncthreads();

            f16x8 af[4], bf[4];
#pragma unroll
            for (int m = 0; m < 4; ++m)
                af[m] = *(const f16x8*)&As[(wr * 64 + m * 16 + lr) * 32 + lk * 8];
#pragma unroll
            for (int n = 0; n < 4; ++n)
                bf[n] = *(const f16x8*)&Bs[(wc * 64 + n * 16 + lr) * 32 + lk * 8];
#pragma unroll
            for (int m = 0; m < 4; ++m)
#pragma unroll
                for (int n = 0; n < 4; ++n)
                    acc[m][n] = __builtin_amdgcn_mfma_f32_16x16x32_f16(
                        af[m], bf[n], acc[m][n], 0, 0, 0);
        }
    }

#pragma unroll
    for (int m = 0; m < 4; ++m) {
        const int row = m0 + wr * 64 + m * 16 + lk * 4;
#pragma unroll
        for (int n = 0; n < 4; ++n) {
            const int col = o0 + wc * 64 + n * 16 + lr;
#pragma unroll
            for (int j = 0; j < 4; ++j)
                atomicAdd(&out[(size_t)(row + j) * D_EMB + col], acc[m][n][j]);
        }
    }
}

extern "C" void kernel_launch(void* const* d_in, const int* in_sizes, int n_in,
                              void* d_out, int out_size, void* d_ws, size_t ws_size,
                              hipStream_t stream) {
    const float* x   = (const float*)d_in[0];
    const float* phi = (const float*)d_in[1];
    const float* Mp  = (const float*)d_in[2];
    const float* Mm  = (const float*)d_in[3];
    float* out = (float*)d_out;

    const size_t S = (size_t)MDIM * KROW;            // 25,165,824
    u16* Up   = (u16*)d_ws;
    u16* Um   = Up + S;
    u16* Mhp  = Um + S;                              // 9,437,184
    u16* Mhm  = Mhp + MELEM;
    u16* xT   = Mhm + MELEM;                         // 1,572,864
    u16* Ttab = xT + (size_t)B_SZ * D_EMB * L_SEQ;   // 2,097,152  (total ~146 MB)

    (void)hipMemsetAsync(d_out, 0, (size_t)out_size * sizeof(float), stream);

    stu_mcvt<<<dim3(2048),                          dim3(256), 0, stream>>>(Mp, Mm, Mhp, Mhm);
    stu_xt  <<<dim3(L_SEQ / 64, D_EMB / 64, B_SZ),  dim3(256), 0, stream>>>(x, xT);
    stu_ttab<<<dim3(16, KF, 2),                     dim3(256), 0, stream>>>(phi, Ttab);

    dim3 g1(L_SEQ / 64, B_SZ * KF, D_EMB / 128);     // 16 x 32 x 6 = 3072
    stu_conv_mfma<<<g1, dim3(256), 0, stream>>>(xT, Ttab, Up, Um);

    stu_spectral_mfma<<<dim3(768), dim3(256), 0, stream>>>(Up, Um, Mhp, Mhm, out);
}

// Round 6
// 228.012 us; speedup vs baseline: 11.6341x; 1.1016x over previous
//
#include <hip/hip_runtime.h>
#include <hip/hip_fp16.h>

typedef unsigned short u16;
typedef unsigned int   u32;
typedef _Float16 f16;
typedef __attribute__((ext_vector_type(8))) f16 f16x8;
typedef __attribute__((ext_vector_type(2))) __fp16 fp16x2;   // cvt_pkrtz return type
typedef __attribute__((ext_vector_type(4))) float f32x4;

#define B_SZ  2
#define L_SEQ 1024
#define D_EMB 768
#define KF    16
#define MDIM  (B_SZ * L_SEQ)   // 2048 GEMM rows
#define KROW  (KF * D_EMB)     // 12288 per-row A length
#define MELEM ((size_t)KF * D_EMB * D_EMB)   // 9,437,184 per M matrix
#define NTILE 96                // 16 m-tiles x 6 o-tiles
#define PT_SZ 16384             // 128x128 partial tile elems

// ---- async global->LDS, 16B per lane (linear LDS dest: wave base + lane*16) ----
__device__ __forceinline__ void gload16(const void* g, void* l) {
    __builtin_amdgcn_global_load_lds(
        (const __attribute__((address_space(1))) u32*)g,
        (__attribute__((address_space(3))) u32*)l, 16, 0, 0);
}

// =====================================================================
// Setup M: Mp/Mm f32 -> fp16 (halves stage-2 B traffic; enables gload-B).
// =====================================================================
__global__ __launch_bounds__(256) void stu_mcvt(const float* __restrict__ Mp,
                                                const float* __restrict__ Mm,
                                                u16* __restrict__ Hp,
                                                u16* __restrict__ Hm) {
    const size_t n8 = MELEM / 8;
    size_t i = (size_t)blockIdx.x * 256 + threadIdx.x;
    const size_t stride = (size_t)gridDim.x * 256;
    for (size_t c = i; c < n8; c += stride) {
        const size_t g = c << 3;
        {
            const float4 a0 = *(const float4*)&Mp[g];
            const float4 a1 = *(const float4*)&Mp[g + 4];
            union { fp16x2 h2[4]; uint4 q; } u;
            u.h2[0] = __builtin_amdgcn_cvt_pkrtz(a0.x, a0.y);
            u.h2[1] = __builtin_amdgcn_cvt_pkrtz(a0.z, a0.w);
            u.h2[2] = __builtin_amdgcn_cvt_pkrtz(a1.x, a1.y);
            u.h2[3] = __builtin_amdgcn_cvt_pkrtz(a1.z, a1.w);
            *(uint4*)&Hp[g] = u.q;
        }
        {
            const float4 a0 = *(const float4*)&Mm[g];
            const float4 a1 = *(const float4*)&Mm[g + 4];
            union { fp16x2 h2[4]; uint4 q; } u;
            u.h2[0] = __builtin_amdgcn_cvt_pkrtz(a0.x, a0.y);
            u.h2[1] = __builtin_amdgcn_cvt_pkrtz(a0.z, a0.w);
            u.h2[2] = __builtin_amdgcn_cvt_pkrtz(a1.x, a1.y);
            u.h2[3] = __builtin_amdgcn_cvt_pkrtz(a1.z, a1.w);
            *(uint4*)&Hm[g] = u.q;
        }
    }
}

// =====================================================================
// Setup A: x -> xT [b][d][s] f16, pre-swizzled (s&63)^((d&7)<<3).
// =====================================================================
__global__ __launch_bounds__(256) void stu_xt(const float* __restrict__ x,
                                              u16* __restrict__ xT) {
    __shared__ __align__(16) float xs[64][68];
    const int s0 = blockIdx.x << 6;
    const int d0 = blockIdx.y << 6;
    const int b  = blockIdx.z;
    const int tid = threadIdx.x;

#pragma unroll
    for (int j = 0; j < 4; ++j) {
        int c = tid + (j << 8);
        int row = c >> 4;
        int col = (c & 15) << 2;
        *(float4*)&xs[row][col] =
            *(const float4*)&x[((size_t)b * L_SEQ + s0 + row) * D_EMB + d0 + col];
    }
    __syncthreads();

    const int dl = tid >> 2;
    const int ss = (tid & 3) << 4;
    const int dg = d0 + dl;
    const int xorv = (dg & 7) << 3;

    union { u16 v[16]; uint4 q[2]; } pk;
#pragma unroll
    for (int u = 0; u < 16; ++u)
        pk.v[u] = __half_as_ushort(__float2half(xs[ss + u][dl]));

    size_t base = (size_t)b * D_EMB * L_SEQ + (size_t)dg * L_SEQ + s0;
    *(uint4*)&xT[base + ( ss      ^ xorv)] = pk.q[0];
    *(uint4*)&xT[base + ((ss + 8) ^ xorv)] = pk.q[1];
}

// =====================================================================
// Setup B: Toeplitz tile table (pre-swizzled).
// =====================================================================
__global__ __launch_bounds__(256) void stu_ttab(const float* __restrict__ phi,
                                                u16* __restrict__ Ttab) {
    const int q    = blockIdx.x;
    const int k    = blockIdx.y;
    const int sign = blockIdx.z;
    const int tid  = threadIdx.x;
    const int tt   = tid >> 2;
    const int ss0  = (tid & 3) << 4;

    union { u16 v[16]; uint4 q4[2]; } pk;
#pragma unroll
    for (int u = 0; u < 16; ++u) {
        int s = (q << 6) + tt - (ss0 + u);
        float v = (s >= 0 && s < L_SEQ) ? phi[s * KF + k] : 0.f;
        if (sign && (s & 1)) v = -v;
        pk.v[u] = __half_as_ushort(__float2half(v));
    }
    const int xorv = (tt & 7) << 3;
    u16* tile = Ttab + (((size_t)(sign * KF + k) * 16 + q) << 12);
    *(uint4*)&tile[(tt << 6) + ( ss0      ^ xorv)] = pk.q4[0];
    *(uint4*)&tile[(tt << 6) + ((ss0 + 8) ^ xorv)] = pk.q4[1];
}

// =====================================================================
// Stage 1 (MFMA conv): unchanged (verified; ~900 TF effective).
// =====================================================================
__global__ __launch_bounds__(256) void stu_conv_mfma(const u16* __restrict__ xT,
                                                     const u16* __restrict__ Ttab,
                                                     u16* __restrict__ Up,
                                                     u16* __restrict__ Um) {
    __shared__ __align__(16) u16 Xs[128 * 64];
    __shared__ __align__(16) u16 Tp[64 * 64];
    __shared__ __align__(16) u16 Tm[64 * 64];

    const int ti = blockIdx.x;
    const int t0 = ti << 6;
    const int b  = blockIdx.y >> 4;
    const int k  = blockIdx.y & 15;
    const int d0 = blockIdx.z << 7;

    const int tid  = threadIdx.x;
    const int lane = tid & 63;
    const int wid  = tid >> 6;
    const int wr   = wid >> 1;
    const int wc   = wid & 1;
    const int lr   = lane & 15;
    const int lk   = lane >> 4;

    f32x4 acc[2][2][4];
#pragma unroll
    for (int s = 0; s < 2; ++s)
#pragma unroll
        for (int m = 0; m < 2; ++m)
#pragma unroll
            for (int n = 0; n < 4; ++n)
                acc[s][m][n] = (f32x4){0.f, 0.f, 0.f, 0.f};

    const u16* xTb = xT + (size_t)b * D_EMB * L_SEQ + (size_t)d0 * L_SEQ;
    const u16* Tpk = Ttab + ((size_t)k * 16) * 4096;
    const u16* Tmk = Ttab + ((size_t)(KF + k) * 16) * 4096;

    for (int r0 = 0; r0 <= t0; r0 += 64) {
        const int q = (t0 - r0) >> 6;
        __syncthreads();
#pragma unroll
        for (int j = 0; j < 4; ++j) {
            int c = tid + (j << 8);
            gload16(xTb + (size_t)(c >> 3) * L_SEQ + r0 + ((c & 7) << 3),
                    &Xs[c << 3]);
        }
        {
            const u16* tp = Tpk + ((size_t)q << 12);
            const u16* tm = Tmk + ((size_t)q << 12);
            gload16(tp + (tid << 3),         &Tp[tid << 3]);
            gload16(tp + ((tid + 256) << 3), &Tp[(tid + 256) << 3]);
            gload16(tm + (tid << 3),         &Tm[tid << 3]);
            gload16(tm + ((tid + 256) << 3), &Tm[(tid + 256) << 3]);
        }
        __syncthreads();

#pragma unroll
        for (int kk = 0; kk < 2; ++kk) {
            f16x8 bfr[4];
#pragma unroll
            for (int n = 0; n < 4; ++n) {
                const int row = (wc << 6) + (n << 4) + lr;
                const int boff = ((kk << 6) + (lk << 4)) ^ ((row & 7) << 4);
                bfr[n] = *(const f16x8*)((const char*)&Xs[0] + row * 128 + boff);
            }
#pragma unroll
            for (int m = 0; m < 2; ++m) {
                const int rowt = (wr << 5) + (m << 4) + lr;
                const int aoff = ((kk << 6) + (lk << 4)) ^ ((rowt & 7) << 4);
                const f16x8 afp = *(const f16x8*)((const char*)&Tp[0] + rowt * 128 + aoff);
                const f16x8 afm = *(const f16x8*)((const char*)&Tm[0] + rowt * 128 + aoff);
#pragma unroll
                for (int n = 0; n < 4; ++n) {
                    acc[0][m][n] = __builtin_amdgcn_mfma_f32_16x16x32_f16(
                        afp, bfr[n], acc[0][m][n], 0, 0, 0);
                    acc[1][m][n] = __builtin_amdgcn_mfma_f32_16x16x32_f16(
                        afm, bfr[n], acc[1][m][n], 0, 0, 0);
                }
            }
        }
    }

#pragma unroll
    for (int m = 0; m < 2; ++m) {
        const int trow = t0 + (wr << 5) + (m << 4) + (lk << 2);
#pragma unroll
        for (int n = 0; n < 4; ++n) {
            const int col = d0 + (wc << 6) + (n << 4) + lr;
#pragma unroll
            for (int j = 0; j < 4; ++j) {
                size_t idx = ((size_t)(b * L_SEQ + trow + j) * KF + k) * D_EMB + col;
                Up[idx] = __half_as_ushort(__float2half(acc[0][m][n][j]));
                Um[idx] = __half_as_ushort(__float2half(acc[1][m][n][j]));
            }
        }
    }
}

// =====================================================================
// Stage 2 (MFMA): fp16 x fp16, both staged via gload with SOURCE-PERMUTED
// 16B chunks (j ^= (row>>1)&3) so ds_read phases spread over all 8 bank
// positions (2-way = free). Epilogue: fp16 split-K partial (if ws fits)
// or f32 atomicAdd fallback.
// =====================================================================
__global__ __launch_bounds__(256) void stu_spectral_mfma(
        const u16* __restrict__ Up, const u16* __restrict__ Um,
        const u16* __restrict__ Mhp, const u16* __restrict__ Mhm,
        float* __restrict__ out, u16* __restrict__ P, int usePartial) {
    __shared__ __align__(16) u16 As[128 * 32];
    __shared__ __align__(16) u16 Bs[128 * 32];

    const int h   = blockIdx.x;
    const int z   = h & 7;                        // XCD slice
    const int rem = h >> 3;                       // 0..95
    const int o0  = (rem % 6) << 7;
    const int m0  = (rem / 6) << 7;
    const int sign = z & 1;
    const int k0 = (z >> 1) << 2;

    const u16* A    = sign ? Um : Up;
    const u16* Bsrc = sign ? Mhm : Mhp;

    const int tid  = threadIdx.x;
    const int lane = tid & 63;
    const int wid  = tid >> 6;
    const int wr   = wid >> 1;
    const int wc   = wid & 1;
    const int lr   = lane & 15;
    const int lk   = lane >> 4;

    f32x4 acc[4][4];
#pragma unroll
    for (int m = 0; m < 4; ++m)
#pragma unroll
        for (int n = 0; n < 4; ++n)
            acc[m][n] = (f32x4){0.f, 0.f, 0.f, 0.f};

    // staging chunk coords: row = c>>2, 16B chunk j = c&3, permuted j^((row>>1)&3)
    const int c0 = tid, c1 = 256 + tid;
    const int r0c = c0 >> 2, j0 = ((c0 & 3) ^ ((c0 >> 3) & 3)) << 3;
    const int r1c = c1 >> 2, j1 = ((c1 & 3) ^ ((c1 >> 3) & 3)) << 3;

    for (int k = k0; k < k0 + 4; ++k) {
        const u16* Ak = A + (size_t)m0 * KROW + k * D_EMB;
        const u16* Bk = Bsrc + (size_t)k * D_EMB * D_EMB + (size_t)o0 * D_EMB;

        for (int ic = 0; ic < D_EMB; ic += 32) {
            __syncthreads();
            gload16(Ak + (size_t)r0c * KROW + ic + j0, &As[c0 << 3]);
            gload16(Ak + (size_t)r1c * KROW + ic + j1, &As[c1 << 3]);
            gload16(Bk + (size_t)r0c * D_EMB + ic + j0, &Bs[c0 << 3]);
            gload16(Bk + (size_t)r1c * D_EMB + ic + j1, &Bs[c1 << 3]);
            __syncthreads();

            f16x8 af[4], bf[4];
#pragma unroll
            for (int m = 0; m < 4; ++m) {
                const int row = wr * 64 + m * 16 + lr;
                af[m] = *(const f16x8*)((const char*)&As[0] + row * 64 +
                                        ((lk ^ ((row >> 1) & 3)) << 4));
            }
#pragma unroll
            for (int n = 0; n < 4; ++n) {
                const int row = wc * 64 + n * 16 + lr;
                bf[n] = *(const f16x8*)((const char*)&Bs[0] + row * 64 +
                                        ((lk ^ ((row >> 1) & 3)) << 4));
            }
#pragma unroll
            for (int m = 0; m < 4; ++m)
#pragma unroll
                for (int n = 0; n < 4; ++n)
                    acc[m][n] = __builtin_amdgcn_mfma_f32_16x16x32_f16(
                        af[m], bf[n], acc[m][n], 0, 0, 0);
        }
    }

    if (usePartial) {
        u16* Pt = P + (size_t)h * PT_SZ;
#pragma unroll
        for (int m = 0; m < 4; ++m) {
            const int rowl = wr * 64 + m * 16 + lk * 4;
#pragma unroll
            for (int n = 0; n < 4; ++n) {
                const int coll = wc * 64 + n * 16 + lr;
#pragma unroll
                for (int j = 0; j < 4; ++j)
                    Pt[(rowl + j) * 128 + coll] =
                        __half_as_ushort(__float2half(acc[m][n][j]));
            }
        }
    } else {
#pragma unroll
        for (int m = 0; m < 4; ++m) {
            const int row = m0 + wr * 64 + m * 16 + lk * 4;
#pragma unroll
            for (int n = 0; n < 4; ++n) {
                const int col = o0 + wc * 64 + n * 16 + lr;
#pragma unroll
                for (int j = 0; j < 4; ++j)
                    atomicAdd(&out[(size_t)(row + j) * D_EMB + col], acc[m][n][j]);
            }
        }
    }
}

// =====================================================================
// Reduce: out[row,col] = sum_z fp16 partials (8 per element).
// =====================================================================
__global__ __launch_bounds__(256) void stu_reduce(const u16* __restrict__ P,
                                                  float* __restrict__ out) {
    const size_t total = (size_t)MDIM * D_EMB;
    size_t idx = (size_t)blockIdx.x * 256 + threadIdx.x;
    const size_t stride = (size_t)gridDim.x * 256;
    for (; idx < total; idx += stride) {
        const int row = (int)(idx / D_EMB);
        const int col = (int)(idx % D_EMB);
        const int tile = (row >> 7) * 6 + (col >> 7);
        const u16* p = P + (size_t)tile * 8 * PT_SZ + ((row & 127) << 7) + (col & 127);
        float s = 0.f;
#pragma unroll
        for (int z = 0; z < 8; ++z)
            s += __half2float(__ushort_as_half(p[z * PT_SZ]));
        out[idx] = s;
    }
}

extern "C" void kernel_launch(void* const* d_in, const int* in_sizes, int n_in,
                              void* d_out, int out_size, void* d_ws, size_t ws_size,
                              hipStream_t stream) {
    const float* x   = (const float*)d_in[0];
    const float* phi = (const float*)d_in[1];
    const float* Mp  = (const float*)d_in[2];
    const float* Mm  = (const float*)d_in[3];
    float* out = (float*)d_out;

    const size_t S = (size_t)MDIM * KROW;            // 25,165,824
    u16* Up   = (u16*)d_ws;
    u16* Um   = Up + S;
    u16* Mhp  = Um + S;
    u16* Mhm  = Mhp + MELEM;
    u16* xT   = Mhm + MELEM;                         // 1,572,864
    u16* Ttab = xT + (size_t)B_SZ * D_EMB * L_SEQ;   // 2,097,152
    u16* Part = Ttab + (size_t)2 * KF * 16 * 4096;   // 12,582,912 (25.2 MB)

    const size_t elems_needed = 2 * S + 2 * MELEM + 1572864 + 2097152 + 12582912;
    const int usePartial = (ws_size >= elems_needed * sizeof(u16)) ? 1 : 0;

    if (!usePartial)
        (void)hipMemsetAsync(d_out, 0, (size_t)out_size * sizeof(float), stream);

    stu_mcvt<<<dim3(2048),                          dim3(256), 0, stream>>>(Mp, Mm, Mhp, Mhm);
    stu_xt  <<<dim3(L_SEQ / 64, D_EMB / 64, B_SZ),  dim3(256), 0, stream>>>(x, xT);
    stu_ttab<<<dim3(16, KF, 2),                     dim3(256), 0, stream>>>(phi, Ttab);

    dim3 g1(L_SEQ / 64, B_SZ * KF, D_EMB / 128);     // 16 x 32 x 6 = 3072
    stu_conv_mfma<<<g1, dim3(256), 0, stream>>>(xT, Ttab, Up, Um);

    stu_spectral_mfma<<<dim3(NTILE * 8), dim3(256), 0, stream>>>(
        Up, Um, Mhp, Mhm, out, Part, usePartial);

    if (usePartial)
        stu_reduce<<<dim3(1536), dim3(256), 0, stream>>>(Part, out);
}

// Round 7
// 211.884 us; speedup vs baseline: 12.5196x; 1.0761x over previous
//
#include <hip/hip_runtime.h>
#include <hip/hip_fp16.h>

typedef unsigned short u16;
typedef unsigned int   u32;
typedef _Float16 f16;
typedef __attribute__((ext_vector_type(8))) f16 f16x8;
typedef __attribute__((ext_vector_type(2))) __fp16 fp16x2;   // cvt_pkrtz return type
typedef __attribute__((ext_vector_type(4))) float f32x4;

#define B_SZ  2
#define L_SEQ 1024
#define D_EMB 768
#define KF    16
#define MDIM  (B_SZ * L_SEQ)   // 2048 GEMM rows
#define KROW  (KF * D_EMB)     // 12288 per-row A length
#define MELEM ((size_t)KF * D_EMB * D_EMB)   // 9,437,184 per M matrix
#define NTILE 96                // 16 m-tiles x 6 o-tiles
#define PT_SZ 16384             // 128x128 partial tile elems

// ---- async global->LDS, 16B per lane (linear LDS dest: wave base + lane*16) ----
__device__ __forceinline__ void gload16(const void* g, void* l) {
    __builtin_amdgcn_global_load_lds(
        (const __attribute__((address_space(1))) u32*)g,
        (__attribute__((address_space(3))) u32*)l, 16, 0, 0);
}

// =====================================================================
// Setup M: Mp/Mm f32 -> fp16.
// =====================================================================
__global__ __launch_bounds__(256) void stu_mcvt(const float* __restrict__ Mp,
                                                const float* __restrict__ Mm,
                                                u16* __restrict__ Hp,
                                                u16* __restrict__ Hm) {
    const size_t n8 = MELEM / 8;
    size_t i = (size_t)blockIdx.x * 256 + threadIdx.x;
    const size_t stride = (size_t)gridDim.x * 256;
    for (size_t c = i; c < n8; c += stride) {
        const size_t g = c << 3;
        {
            const float4 a0 = *(const float4*)&Mp[g];
            const float4 a1 = *(const float4*)&Mp[g + 4];
            union { fp16x2 h2[4]; uint4 q; } u;
            u.h2[0] = __builtin_amdgcn_cvt_pkrtz(a0.x, a0.y);
            u.h2[1] = __builtin_amdgcn_cvt_pkrtz(a0.z, a0.w);
            u.h2[2] = __builtin_amdgcn_cvt_pkrtz(a1.x, a1.y);
            u.h2[3] = __builtin_amdgcn_cvt_pkrtz(a1.z, a1.w);
            *(uint4*)&Hp[g] = u.q;
        }
        {
            const float4 a0 = *(const float4*)&Mm[g];
            const float4 a1 = *(const float4*)&Mm[g + 4];
            union { fp16x2 h2[4]; uint4 q; } u;
            u.h2[0] = __builtin_amdgcn_cvt_pkrtz(a0.x, a0.y);
            u.h2[1] = __builtin_amdgcn_cvt_pkrtz(a0.z, a0.w);
            u.h2[2] = __builtin_amdgcn_cvt_pkrtz(a1.x, a1.y);
            u.h2[3] = __builtin_amdgcn_cvt_pkrtz(a1.z, a1.w);
            *(uint4*)&Hm[g] = u.q;
        }
    }
}

// =====================================================================
// Setup A: x -> xT [b][d][s] f16, pre-swizzled (s&63)^((d&7)<<3).
// =====================================================================
__global__ __launch_bounds__(256) void stu_xt(const float* __restrict__ x,
                                              u16* __restrict__ xT) {
    __shared__ __align__(16) float xs[64][68];
    const int s0 = blockIdx.x << 6;
    const int d0 = blockIdx.y << 6;
    const int b  = blockIdx.z;
    const int tid = threadIdx.x;

#pragma unroll
    for (int j = 0; j < 4; ++j) {
        int c = tid + (j << 8);
        int row = c >> 4;
        int col = (c & 15) << 2;
        *(float4*)&xs[row][col] =
            *(const float4*)&x[((size_t)b * L_SEQ + s0 + row) * D_EMB + d0 + col];
    }
    __syncthreads();

    const int dl = tid >> 2;
    const int ss = (tid & 3) << 4;
    const int dg = d0 + dl;
    const int xorv = (dg & 7) << 3;

    union { u16 v[16]; uint4 q[2]; } pk;
#pragma unroll
    for (int u = 0; u < 16; ++u)
        pk.v[u] = __half_as_ushort(__float2half(xs[ss + u][dl]));

    size_t base = (size_t)b * D_EMB * L_SEQ + (size_t)dg * L_SEQ + s0;
    *(uint4*)&xT[base + ( ss      ^ xorv)] = pk.q[0];
    *(uint4*)&xT[base + ((ss + 8) ^ xorv)] = pk.q[1];
}

// =====================================================================
// Setup B: Toeplitz tile table (pre-swizzled).
// =====================================================================
__global__ __launch_bounds__(256) void stu_ttab(const float* __restrict__ phi,
                                                u16* __restrict__ Ttab) {
    const int q    = blockIdx.x;
    const int k    = blockIdx.y;
    const int sign = blockIdx.z;
    const int tid  = threadIdx.x;
    const int tt   = tid >> 2;
    const int ss0  = (tid & 3) << 4;

    union { u16 v[16]; uint4 q4[2]; } pk;
#pragma unroll
    for (int u = 0; u < 16; ++u) {
        int s = (q << 6) + tt - (ss0 + u);
        float v = (s >= 0 && s < L_SEQ) ? phi[s * KF + k] : 0.f;
        if (sign && (s & 1)) v = -v;
        pk.v[u] = __half_as_ushort(__float2half(v));
    }
    const int xorv = (tt & 7) << 3;
    u16* tile = Ttab + (((size_t)(sign * KF + k) * 16 + q) << 12);
    *(uint4*)&tile[(tt << 6) + ( ss0      ^ xorv)] = pk.q4[0];
    *(uint4*)&tile[(tt << 6) + ((ss0 + 8) ^ xorv)] = pk.q4[1];
}

// =====================================================================
// Stage 1 (MFMA conv): 64t x 192d tile (was 128d) -> 48 MFMA/wave/iter.
// LPT: ti reversed so longest blocks dispatch first.
// =====================================================================
__global__ __launch_bounds__(256) void stu_conv_mfma(const u16* __restrict__ xT,
                                                     const u16* __restrict__ Ttab,
                                                     u16* __restrict__ Up,
                                                     u16* __restrict__ Um) {
    __shared__ __align__(16) u16 Xs[192 * 64];   // 24 KB
    __shared__ __align__(16) u16 Tp[64 * 64];    // 8 KB
    __shared__ __align__(16) u16 Tm[64 * 64];    // 8 KB

    const int ti = 15 - blockIdx.x;              // LPT: long blocks first
    const int t0 = ti << 6;
    const int b  = blockIdx.y >> 4;
    const int k  = blockIdx.y & 15;
    const int d0 = blockIdx.z * 192;

    const int tid  = threadIdx.x;
    const int lane = tid & 63;
    const int wid  = tid >> 6;
    const int wr   = wid >> 1;        // t-half (32 rows)
    const int wc   = wid & 1;         // d-half (96 cols)
    const int lr   = lane & 15;
    const int lk   = lane >> 4;

    f32x4 acc[2][2][6];               // [sign][m][n]
#pragma unroll
    for (int s = 0; s < 2; ++s)
#pragma unroll
        for (int m = 0; m < 2; ++m)
#pragma unroll
            for (int n = 0; n < 6; ++n)
                acc[s][m][n] = (f32x4){0.f, 0.f, 0.f, 0.f};

    const u16* xTb = xT + (size_t)b * D_EMB * L_SEQ + (size_t)d0 * L_SEQ;
    const u16* Tpk = Ttab + ((size_t)k * 16) * 4096;
    const u16* Tmk = Ttab + ((size_t)(KF + k) * 16) * 4096;

    for (int r0 = 0; r0 <= t0; r0 += 64) {
        const int q = (t0 - r0) >> 6;
        __syncthreads();
        // ---- stage xT tile: 192 rows x 128B = 1536 chunks ----
#pragma unroll
        for (int j = 0; j < 6; ++j) {
            int c = tid + (j << 8);
            gload16(xTb + (size_t)(c >> 3) * L_SEQ + r0 + ((c & 7) << 3),
                    &Xs[c << 3]);
        }
        // ---- stage Toeplitz tiles ----
        {
            const u16* tp = Tpk + ((size_t)q << 12);
            const u16* tm = Tmk + ((size_t)q << 12);
            gload16(tp + (tid << 3),         &Tp[tid << 3]);
            gload16(tp + ((tid + 256) << 3), &Tp[(tid + 256) << 3]);
            gload16(tm + (tid << 3),         &Tm[tid << 3]);
            gload16(tm + ((tid + 256) << 3), &Tm[(tid + 256) << 3]);
        }
        __syncthreads();

#pragma unroll
        for (int kk = 0; kk < 2; ++kk) {
            f16x8 bfr[6];
#pragma unroll
            for (int n = 0; n < 6; ++n) {
                const int row = wc * 96 + (n << 4) + lr;
                const int boff = ((kk << 6) + (lk << 4)) ^ ((row & 7) << 4);
                bfr[n] = *(const f16x8*)((const char*)&Xs[0] + row * 128 + boff);
            }
#pragma unroll
            for (int m = 0; m < 2; ++m) {
                const int rowt = (wr << 5) + (m << 4) + lr;
                const int aoff = ((kk << 6) + (lk << 4)) ^ ((rowt & 7) << 4);
                const f16x8 afp = *(const f16x8*)((const char*)&Tp[0] + rowt * 128 + aoff);
                const f16x8 afm = *(const f16x8*)((const char*)&Tm[0] + rowt * 128 + aoff);
#pragma unroll
                for (int n = 0; n < 6; ++n) {
                    acc[0][m][n] = __builtin_amdgcn_mfma_f32_16x16x32_f16(
                        afp, bfr[n], acc[0][m][n], 0, 0, 0);
                    acc[1][m][n] = __builtin_amdgcn_mfma_f32_16x16x32_f16(
                        afm, bfr[n], acc[1][m][n], 0, 0, 0);
                }
            }
        }
    }

    // epilogue: t row = m*16 + lk*4 + j, d col = n*16 + lr
#pragma unroll
    for (int m = 0; m < 2; ++m) {
        const int trow = t0 + (wr << 5) + (m << 4) + (lk << 2);
#pragma unroll
        for (int n = 0; n < 6; ++n) {
            const int col = d0 + wc * 96 + (n << 4) + lr;
#pragma unroll
            for (int j = 0; j < 4; ++j) {
                size_t idx = ((size_t)(b * L_SEQ + trow + j) * KF + k) * D_EMB + col;
                Up[idx] = __half_as_ushort(__float2half(acc[0][m][n][j]));
                Um[idx] = __half_as_ushort(__float2half(acc[1][m][n][j]));
            }
        }
    }
}

// =====================================================================
// Stage 2 (MFMA): BK=64 (was 32) -> 32 MFMA/wave per barrier-pair.
// 128B LDS rows; full 8-chunk XOR swizzle (source-permuted gload + same
// involution on ds_read). Split-K fp16 partials (ws-gated) or atomics.
// =====================================================================
__global__ __launch_bounds__(256) void stu_spectral_mfma(
        const u16* __restrict__ Up, const u16* __restrict__ Um,
        const u16* __restrict__ Mhp, const u16* __restrict__ Mhm,
        float* __restrict__ out, u16* __restrict__ P, int usePartial) {
    __shared__ __align__(16) u16 As[128 * 64];   // 16 KB
    __shared__ __align__(16) u16 Bs[128 * 64];   // 16 KB

    const int h   = blockIdx.x;
    const int z   = h & 7;                        // XCD slice
    const int rem = h >> 3;                       // 0..95
    const int o0  = (rem % 6) << 7;
    const int m0  = (rem / 6) << 7;
    const int sign = z & 1;
    const int k0 = (z >> 1) << 2;

    const u16* A    = sign ? Um : Up;
    const u16* Bsrc = sign ? Mhm : Mhp;

    const int tid  = threadIdx.x;
    const int lane = tid & 63;
    const int wid  = tid >> 6;
    const int wr   = wid >> 1;
    const int wc   = wid & 1;
    const int lr   = lane & 15;
    const int lk   = lane >> 4;

    f32x4 acc[4][4];
#pragma unroll
    for (int m = 0; m < 4; ++m)
#pragma unroll
        for (int n = 0; n < 4; ++n)
            acc[m][n] = (f32x4){0.f, 0.f, 0.f, 0.f};

    for (int k = k0; k < k0 + 4; ++k) {
        const u16* Ak = A + (size_t)m0 * KROW + k * D_EMB;
        const u16* Bk = Bsrc + (size_t)k * D_EMB * D_EMB + (size_t)o0 * D_EMB;

        for (int ic = 0; ic < D_EMB; ic += 64) {
            __syncthreads();
            // 128 rows x 64 f16 each; 8 chunks/row, source-permuted c^(row&7)
#pragma unroll
            for (int j = 0; j < 4; ++j) {
                const int c = tid + (j << 8);
                const int row = c >> 3;
                const int off = ((c & 7) ^ (row & 7)) << 3;
                gload16(Ak + (size_t)row * KROW + ic + off, &As[c << 3]);
                gload16(Bk + (size_t)row * D_EMB + ic + off, &Bs[c << 3]);
            }
            __syncthreads();

#pragma unroll
            for (int kk = 0; kk < 2; ++kk) {
                f16x8 af[4], bf[4];
#pragma unroll
                for (int m = 0; m < 4; ++m) {
                    const int row = wr * 64 + (m << 4) + lr;
                    const int boff = (((kk << 2) + lk) ^ (row & 7)) << 4;
                    af[m] = *(const f16x8*)((const char*)&As[0] + row * 128 + boff);
                }
#pragma unroll
                for (int n = 0; n < 4; ++n) {
                    const int row = wc * 64 + (n << 4) + lr;
                    const int boff = (((kk << 2) + lk) ^ (row & 7)) << 4;
                    bf[n] = *(const f16x8*)((const char*)&Bs[0] + row * 128 + boff);
                }
#pragma unroll
                for (int m = 0; m < 4; ++m)
#pragma unroll
                    for (int n = 0; n < 4; ++n)
                        acc[m][n] = __builtin_amdgcn_mfma_f32_16x16x32_f16(
                            af[m], bf[n], acc[m][n], 0, 0, 0);
            }
        }
    }

    if (usePartial) {
        u16* Pt = P + (size_t)h * PT_SZ;
#pragma unroll
        for (int m = 0; m < 4; ++m) {
            const int rowl = wr * 64 + (m << 4) + (lk << 2);
#pragma unroll
            for (int n = 0; n < 4; ++n) {
                const int coll = wc * 64 + (n << 4) + lr;
#pragma unroll
                for (int j = 0; j < 4; ++j)
                    Pt[(rowl + j) * 128 + coll] =
                        __half_as_ushort(__float2half(acc[m][n][j]));
            }
        }
    } else {
#pragma unroll
        for (int m = 0; m < 4; ++m) {
            const int row = m0 + wr * 64 + (m << 4) + (lk << 2);
#pragma unroll
            for (int n = 0; n < 4; ++n) {
                const int col = o0 + wc * 64 + (n << 4) + lr;
#pragma unroll
                for (int j = 0; j < 4; ++j)
                    atomicAdd(&out[(size_t)(row + j) * D_EMB + col], acc[m][n][j]);
            }
        }
    }
}

// =====================================================================
// Reduce: out[row,col] = sum_z fp16 partials (8 per element).
// =====================================================================
__global__ __launch_bounds__(256) void stu_reduce(const u16* __restrict__ P,
                                                  float* __restrict__ out) {
    const size_t total = (size_t)MDIM * D_EMB;
    size_t idx = (size_t)blockIdx.x * 256 + threadIdx.x;
    const size_t stride = (size_t)gridDim.x * 256;
    for (; idx < total; idx += stride) {
        const int row = (int)(idx / D_EMB);
        const int col = (int)(idx % D_EMB);
        const int tile = (row >> 7) * 6 + (col >> 7);
        const u16* p = P + (size_t)tile * 8 * PT_SZ + ((row & 127) << 7) + (col & 127);
        float s = 0.f;
#pragma unroll
        for (int z = 0; z < 8; ++z)
            s += __half2float(__ushort_as_half(p[z * PT_SZ]));
        out[idx] = s;
    }
}

extern "C" void kernel_launch(void* const* d_in, const int* in_sizes, int n_in,
                              void* d_out, int out_size, void* d_ws, size_t ws_size,
                              hipStream_t stream) {
    const float* x   = (const float*)d_in[0];
    const float* phi = (const float*)d_in[1];
    const float* Mp  = (const float*)d_in[2];
    const float* Mm  = (const float*)d_in[3];
    float* out = (float*)d_out;

    const size_t S = (size_t)MDIM * KROW;            // 25,165,824
    u16* Up   = (u16*)d_ws;
    u16* Um   = Up + S;
    u16* Mhp  = Um + S;
    u16* Mhm  = Mhp + MELEM;
    u16* xT   = Mhm + MELEM;                         // 1,572,864
    u16* Ttab = xT + (size_t)B_SZ * D_EMB * L_SEQ;   // 2,097,152
    u16* Part = Ttab + (size_t)2 * KF * 16 * 4096;   // 12,582,912 (25.2 MB)

    const size_t elems_needed = 2 * S + 2 * MELEM + 1572864 + 2097152 + 12582912;
    const int usePartial = (ws_size >= elems_needed * sizeof(u16)) ? 1 : 0;

    if (!usePartial)
        (void)hipMemsetAsync(d_out, 0, (size_t)out_size * sizeof(float), stream);

    stu_mcvt<<<dim3(2048),                          dim3(256), 0, stream>>>(Mp, Mm, Mhp, Mhm);
    stu_xt  <<<dim3(L_SEQ / 64, D_EMB / 64, B_SZ),  dim3(256), 0, stream>>>(x, xT);
    stu_ttab<<<dim3(16, KF, 2),                     dim3(256), 0, stream>>>(phi, Ttab);

    dim3 g1(L_SEQ / 64, B_SZ * KF, D_EMB / 192);     // 16 x 32 x 4 = 2048
    stu_conv_mfma<<<g1, dim3(256), 0, stream>>>(xT, Ttab, Up, Um);

    stu_spectral_mfma<<<dim3(NTILE * 8), dim3(256), 0, stream>>>(
        Up, Um, Mhp, Mhm, out, Part, usePartial);

    if (usePartial)
        stu_reduce<<<dim3(1536), dim3(256), 0, stream>>>(Part, out);
}

// Round 8
// 171.508 us; speedup vs baseline: 15.4670x; 1.2354x over previous
//
#include <hip/hip_runtime.h>
#include <hip/hip_fp16.h>

typedef unsigned short u16;
typedef unsigned int   u32;
typedef _Float16 f16;
typedef __attribute__((ext_vector_type(8))) f16 f16x8;
typedef __attribute__((ext_vector_type(2))) __fp16 fp16x2;   // cvt_pkrtz return type
typedef __attribute__((ext_vector_type(4))) float f32x4;

#define B_SZ  2
#define L_SEQ 1024
#define D_EMB 768
#define KF    16
#define MDIM  (B_SZ * L_SEQ)   // 2048 GEMM rows
#define KROW  (KF * D_EMB)     // 12288 per-row A length
#define MELEM ((size_t)KF * D_EMB * D_EMB)   // 9,437,184 per M matrix
#define NTILE 96                // 16 m-tiles x 6 o-tiles
#define PT_SZ 16384             // 128x128 partial tile elems

// ---- async global->LDS, 16B per lane (linear LDS dest: wave base + lane*16) ----
__device__ __forceinline__ void gload16(const void* g, void* l) {
    __builtin_amdgcn_global_load_lds(
        (const __attribute__((address_space(1))) u32*)g,
        (__attribute__((address_space(3))) u32*)l, 16, 0, 0);
}

// =====================================================================
// Setup (fused): blocks 0..383 transpose x -> xT (pre-swizzled);
// blocks 384..895 build the Toeplitz tile table (pre-swizzled).
// =====================================================================
__global__ __launch_bounds__(256) void stu_setup(const float* __restrict__ x,
                                                 const float* __restrict__ phi,
                                                 u16* __restrict__ xT,
                                                 u16* __restrict__ Ttab) {
    __shared__ __align__(16) float xs[64][68];
    const int bid = blockIdx.x;
    const int tid = threadIdx.x;

    if (bid < 384) {
        // ---- xT: x[b][s][d] f32 -> xT[b][d][s] f16, swz (s&63)^((d&7)<<3) ----
        const int s0 = (bid & 15) << 6;
        const int d0 = ((bid >> 4) % 12) << 6;
        const int b  = bid / 192;

#pragma unroll
        for (int j = 0; j < 4; ++j) {
            int c = tid + (j << 8);
            int row = c >> 4;
            int col = (c & 15) << 2;
            *(float4*)&xs[row][col] =
                *(const float4*)&x[((size_t)b * L_SEQ + s0 + row) * D_EMB + d0 + col];
        }
        __syncthreads();

        const int dl = tid >> 2;
        const int ss = (tid & 3) << 4;
        const int dg = d0 + dl;
        const int xorv = (dg & 7) << 3;

        union { u16 v[16]; uint4 q[2]; } pk;
#pragma unroll
        for (int u = 0; u < 16; ++u)
            pk.v[u] = __half_as_ushort(__float2half(xs[ss + u][dl]));

        size_t base = (size_t)b * D_EMB * L_SEQ + (size_t)dg * L_SEQ + s0;
        *(uint4*)&xT[base + ( ss      ^ xorv)] = pk.q[0];
        *(uint4*)&xT[base + ((ss + 8) ^ xorv)] = pk.q[1];
    } else {
        // ---- Ttab[sign][k][q]: 64x64 tile, T[tt][ss]=(+/-)^s phi[s], s=64q+tt-ss ----
        const int f    = bid - 384;
        const int q    = f & 15;
        const int k    = (f >> 4) & 15;
        const int sign = f >> 8;
        const int tt   = tid >> 2;
        const int ss0  = (tid & 3) << 4;

        union { u16 v[16]; uint4 q4[2]; } pk;
#pragma unroll
        for (int u = 0; u < 16; ++u) {
            int s = (q << 6) + tt - (ss0 + u);
            float v = (s >= 0 && s < L_SEQ) ? phi[s * KF + k] : 0.f;
            if (sign && (s & 1)) v = -v;
            pk.v[u] = __half_as_ushort(__float2half(v));
        }
        const int xorv = (tt & 7) << 3;
        u16* tile = Ttab + (((size_t)(sign * KF + k) * 16 + q) << 12);
        *(uint4*)&tile[(tt << 6) + ( ss0      ^ xorv)] = pk.q4[0];
        *(uint4*)&tile[(tt << 6) + ((ss0 + 8) ^ xorv)] = pk.q4[1];
    }
}

// =====================================================================
// Stage 1 (fused): blocks 0..511 convert M f32->f16 (overlaps with conv);
// blocks 512+ do the MFMA conv with 2-PHASE PREFETCH (T3-min):
//   prologue stage buf0; per iter: issue stage(buf^1, next) -> compute(buf)
//   -> one __syncthreads (drains prefetch, latency hidden under MFMA).
// LDS 80KB dbuf -> 2 blocks/CU.
// =====================================================================
__global__ __launch_bounds__(256) void stu_conv_mcvt(
        const u16* __restrict__ xT, const u16* __restrict__ Ttab,
        u16* __restrict__ Up, u16* __restrict__ Um,
        const float* __restrict__ Mp, const float* __restrict__ Mm,
        u16* __restrict__ Hp, u16* __restrict__ Hm) {
    __shared__ __align__(16) u16 Xs[2][192 * 64];   // 48 KB
    __shared__ __align__(16) u16 Tps[2][64 * 64];   // 16 KB
    __shared__ __align__(16) u16 Tms[2][64 * 64];   // 16 KB

    const int bid = blockIdx.x;
    const int tid = threadIdx.x;

    if (bid < 512) {
        // ---- mcvt: M f32 -> fp16, grid-stride over 512 blocks ----
        const size_t n8 = MELEM / 8;
        size_t i = (size_t)bid * 256 + tid;
        const size_t stride = (size_t)512 * 256;
        for (size_t cc = i; cc < n8; cc += stride) {
            const size_t g = cc << 3;
            {
                const float4 a0 = *(const float4*)&Mp[g];
                const float4 a1 = *(const float4*)&Mp[g + 4];
                union { fp16x2 h2[4]; uint4 q; } u;
                u.h2[0] = __builtin_amdgcn_cvt_pkrtz(a0.x, a0.y);
                u.h2[1] = __builtin_amdgcn_cvt_pkrtz(a0.z, a0.w);
                u.h2[2] = __builtin_amdgcn_cvt_pkrtz(a1.x, a1.y);
                u.h2[3] = __builtin_amdgcn_cvt_pkrtz(a1.z, a1.w);
                *(uint4*)&Hp[g] = u.q;
            }
            {
                const float4 a0 = *(const float4*)&Mm[g];
                const float4 a1 = *(const float4*)&Mm[g + 4];
                union { fp16x2 h2[4]; uint4 q; } u;
                u.h2[0] = __builtin_amdgcn_cvt_pkrtz(a0.x, a0.y);
                u.h2[1] = __builtin_amdgcn_cvt_pkrtz(a0.z, a0.w);
                u.h2[2] = __builtin_amdgcn_cvt_pkrtz(a1.x, a1.y);
                u.h2[3] = __builtin_amdgcn_cvt_pkrtz(a1.z, a1.w);
                *(uint4*)&Hm[g] = u.q;
            }
        }
        return;
    }

    // ---- conv ----
    const int c  = bid - 512;
    const int ti = 15 - (c >> 7);                // LPT: long blocks first
    const int t0 = ti << 6;
    const int rr = c & 127;
    const int b  = (rr >> 2) >> 4;
    const int k  = (rr >> 2) & 15;
    const int d0 = (rr & 3) * 192;

    const int lane = tid & 63;
    const int wid  = tid >> 6;
    const int wr   = wid >> 1;        // t-half (32 rows)
    const int wc   = wid & 1;         // d-half (96 cols)
    const int lr   = lane & 15;
    const int lk   = lane >> 4;

    f32x4 acc[2][2][6];               // [sign][m][n]
#pragma unroll
    for (int s = 0; s < 2; ++s)
#pragma unroll
        for (int m = 0; m < 2; ++m)
#pragma unroll
            for (int n = 0; n < 6; ++n)
                acc[s][m][n] = (f32x4){0.f, 0.f, 0.f, 0.f};

    const u16* xTb = xT + (size_t)b * D_EMB * L_SEQ + (size_t)d0 * L_SEQ;
    const u16* Tpk = Ttab + ((size_t)k * 16) * 4096;
    const u16* Tmk = Ttab + ((size_t)(KF + k) * 16) * 4096;

    // ---- staging helpers (1536 X chunks, 512+512 T chunks) ----
    auto stageX = [&](int buf, int r0) {
#pragma unroll
        for (int j = 0; j < 6; ++j) {
            int cc = tid + (j << 8);
            gload16(xTb + (size_t)(cc >> 3) * L_SEQ + r0 + ((cc & 7) << 3),
                    &Xs[buf][cc << 3]);
        }
    };
    auto stageT = [&](int buf, int q) {
        const u16* tp = Tpk + ((size_t)q << 12);
        const u16* tm = Tmk + ((size_t)q << 12);
        gload16(tp + (tid << 3),         &Tps[buf][tid << 3]);
        gload16(tp + ((tid + 256) << 3), &Tps[buf][(tid + 256) << 3]);
        gload16(tm + (tid << 3),         &Tms[buf][tid << 3]);
        gload16(tm + ((tid + 256) << 3), &Tms[buf][(tid + 256) << 3]);
    };

    // prologue: buf0 <- r0=0 (q=ti)
    stageX(0, 0);
    stageT(0, ti);
    __syncthreads();

    int cur = 0;
    for (int r0 = 0; r0 <= t0; r0 += 64) {
        // prefetch next tile into cur^1 (latency hidden under MFMA below)
        if (r0 < t0) {
            stageX(cur ^ 1, r0 + 64);
            stageT(cur ^ 1, ((t0 - r0) >> 6) - 1);
        }

        const char* XsC = (const char*)&Xs[cur][0];
        const char* TpC = (const char*)&Tps[cur][0];
        const char* TmC = (const char*)&Tms[cur][0];

#pragma unroll
        for (int kk = 0; kk < 2; ++kk) {
            f16x8 bfr[6];
#pragma unroll
            for (int n = 0; n < 6; ++n) {
                const int row = wc * 96 + (n << 4) + lr;
                const int boff = ((kk << 6) + (lk << 4)) ^ ((row & 7) << 4);
                bfr[n] = *(const f16x8*)(XsC + row * 128 + boff);
            }
#pragma unroll
            for (int m = 0; m < 2; ++m) {
                const int rowt = (wr << 5) + (m << 4) + lr;
                const int aoff = ((kk << 6) + (lk << 4)) ^ ((rowt & 7) << 4);
                const f16x8 afp = *(const f16x8*)(TpC + rowt * 128 + aoff);
                const f16x8 afm = *(const f16x8*)(TmC + rowt * 128 + aoff);
#pragma unroll
                for (int n = 0; n < 6; ++n) {
                    acc[0][m][n] = __builtin_amdgcn_mfma_f32_16x16x32_f16(
                        afp, bfr[n], acc[0][m][n], 0, 0, 0);
                    acc[1][m][n] = __builtin_amdgcn_mfma_f32_16x16x32_f16(
                        afm, bfr[n], acc[1][m][n], 0, 0, 0);
                }
            }
        }
        __syncthreads();   // drains prefetch vmcnt + protects buffer swap
        cur ^= 1;
    }

    // epilogue: t row = m*16 + lk*4 + j, d col = n*16 + lr
#pragma unroll
    for (int m = 0; m < 2; ++m) {
        const int trow = t0 + (wr << 5) + (m << 4) + (lk << 2);
#pragma unroll
        for (int n = 0; n < 6; ++n) {
            const int col = d0 + wc * 96 + (n << 4) + lr;
#pragma unroll
            for (int j = 0; j < 4; ++j) {
                size_t idx = ((size_t)(b * L_SEQ + trow + j) * KF + k) * D_EMB + col;
                Up[idx] = __half_as_ushort(__float2half(acc[0][m][n][j]));
                Um[idx] = __half_as_ushort(__float2half(acc[1][m][n][j]));
            }
        }
    }
}

// =====================================================================
// Stage 2 (MFMA): BK=64, 8-chunk XOR swizzle, split-K partials (verified).
// =====================================================================
__global__ __launch_bounds__(256) void stu_spectral_mfma(
        const u16* __restrict__ Up, const u16* __restrict__ Um,
        const u16* __restrict__ Mhp, const u16* __restrict__ Mhm,
        float* __restrict__ out, u16* __restrict__ P, int usePartial) {
    __shared__ __align__(16) u16 As[128 * 64];   // 16 KB
    __shared__ __align__(16) u16 Bs[128 * 64];   // 16 KB

    const int h   = blockIdx.x;
    const int z   = h & 7;                        // XCD slice
    const int rem = h >> 3;                       // 0..95
    const int o0  = (rem % 6) << 7;
    const int m0  = (rem / 6) << 7;
    const int sign = z & 1;
    const int k0 = (z >> 1) << 2;

    const u16* A    = sign ? Um : Up;
    const u16* Bsrc = sign ? Mhm : Mhp;

    const int tid  = threadIdx.x;
    const int lane = tid & 63;
    const int wid  = tid >> 6;
    const int wr   = wid >> 1;
    const int wc   = wid & 1;
    const int lr   = lane & 15;
    const int lk   = lane >> 4;

    f32x4 acc[4][4];
#pragma unroll
    for (int m = 0; m < 4; ++m)
#pragma unroll
        for (int n = 0; n < 4; ++n)
            acc[m][n] = (f32x4){0.f, 0.f, 0.f, 0.f};

    for (int k = k0; k < k0 + 4; ++k) {
        const u16* Ak = A + (size_t)m0 * KROW + k * D_EMB;
        const u16* Bk = Bsrc + (size_t)k * D_EMB * D_EMB + (size_t)o0 * D_EMB;

        for (int ic = 0; ic < D_EMB; ic += 64) {
            __syncthreads();
#pragma unroll
            for (int j = 0; j < 4; ++j) {
                const int c = tid + (j << 8);
                const int row = c >> 3;
                const int off = ((c & 7) ^ (row & 7)) << 3;
                gload16(Ak + (size_t)row * KROW + ic + off, &As[c << 3]);
                gload16(Bk + (size_t)row * D_EMB + ic + off, &Bs[c << 3]);
            }
            __syncthreads();

#pragma unroll
            for (int kk = 0; kk < 2; ++kk) {
                f16x8 af[4], bf[4];
#pragma unroll
                for (int m = 0; m < 4; ++m) {
                    const int row = wr * 64 + (m << 4) + lr;
                    const int boff = (((kk << 2) + lk) ^ (row & 7)) << 4;
                    af[m] = *(const f16x8*)((const char*)&As[0] + row * 128 + boff);
                }
#pragma unroll
                for (int n = 0; n < 4; ++n) {
                    const int row = wc * 64 + (n << 4) + lr;
                    const int boff = (((kk << 2) + lk) ^ (row & 7)) << 4;
                    bf[n] = *(const f16x8*)((const char*)&Bs[0] + row * 128 + boff);
                }
#pragma unroll
                for (int m = 0; m < 4; ++m)
#pragma unroll
                    for (int n = 0; n < 4; ++n)
                        acc[m][n] = __builtin_amdgcn_mfma_f32_16x16x32_f16(
                            af[m], bf[n], acc[m][n], 0, 0, 0);
            }
        }
    }

    if (usePartial) {
        u16* Pt = P + (size_t)h * PT_SZ;
#pragma unroll
        for (int m = 0; m < 4; ++m) {
            const int rowl = wr * 64 + (m << 4) + (lk << 2);
#pragma unroll
            for (int n = 0; n < 4; ++n) {
                const int coll = wc * 64 + (n << 4) + lr;
#pragma unroll
                for (int j = 0; j < 4; ++j)
                    Pt[(rowl + j) * 128 + coll] =
                        __half_as_ushort(__float2half(acc[m][n][j]));
            }
        }
    } else {
#pragma unroll
        for (int m = 0; m < 4; ++m) {
            const int row = m0 + wr * 64 + (m << 4) + (lk << 2);
#pragma unroll
            for (int n = 0; n < 4; ++n) {
                const int col = o0 + wc * 64 + (n << 4) + lr;
#pragma unroll
                for (int j = 0; j < 4; ++j)
                    atomicAdd(&out[(size_t)(row + j) * D_EMB + col], acc[m][n][j]);
            }
        }
    }
}

// =====================================================================
// Reduce: out[row,col] = sum_z fp16 partials (8 per element).
// =====================================================================
__global__ __launch_bounds__(256) void stu_reduce(const u16* __restrict__ P,
                                                  float* __restrict__ out) {
    const size_t total = (size_t)MDIM * D_EMB;
    size_t idx = (size_t)blockIdx.x * 256 + threadIdx.x;
    const size_t stride = (size_t)gridDim.x * 256;
    for (; idx < total; idx += stride) {
        const int row = (int)(idx / D_EMB);
        const int col = (int)(idx % D_EMB);
        const int tile = (row >> 7) * 6 + (col >> 7);
        const u16* p = P + (size_t)tile * 8 * PT_SZ + ((row & 127) << 7) + (col & 127);
        float s = 0.f;
#pragma unroll
        for (int z = 0; z < 8; ++z)
            s += __half2float(__ushort_as_half(p[z * PT_SZ]));
        out[idx] = s;
    }
}

extern "C" void kernel_launch(void* const* d_in, const int* in_sizes, int n_in,
                              void* d_out, int out_size, void* d_ws, size_t ws_size,
                              hipStream_t stream) {
    const float* x   = (const float*)d_in[0];
    const float* phi = (const float*)d_in[1];
    const float* Mp  = (const float*)d_in[2];
    const float* Mm  = (const float*)d_in[3];
    float* out = (float*)d_out;

    const size_t S = (size_t)MDIM * KROW;            // 25,165,824
    u16* Up   = (u16*)d_ws;
    u16* Um   = Up + S;
    u16* Mhp  = Um + S;
    u16* Mhm  = Mhp + MELEM;
    u16* xT   = Mhm + MELEM;                         // 1,572,864
    u16* Ttab = xT + (size_t)B_SZ * D_EMB * L_SEQ;   // 2,097,152
    u16* Part = Ttab + (size_t)2 * KF * 16 * 4096;   // 12,582,912 (25.2 MB)

    const size_t elems_needed = 2 * S + 2 * MELEM + 1572864 + 2097152 + 12582912;
    const int usePartial = (ws_size >= elems_needed * sizeof(u16)) ? 1 : 0;

    if (!usePartial)
        (void)hipMemsetAsync(d_out, 0, (size_t)out_size * sizeof(float), stream);

    stu_setup<<<dim3(896), dim3(256), 0, stream>>>(x, phi, xT, Ttab);

    // 512 mcvt blocks (dispatch first, overlap) + 2048 conv blocks
    stu_conv_mcvt<<<dim3(2560), dim3(256), 0, stream>>>(
        xT, Ttab, Up, Um, Mp, Mm, Mhp, Mhm);

    stu_spectral_mfma<<<dim3(NTILE * 8), dim3(256), 0, stream>>>(
        Up, Um, Mhp, Mhm, out, Part, usePartial);

    if (usePartial)
        stu_reduce<<<dim3(1536), dim3(256), 0, stream>>>(Part, out);
}